// Round 1
// baseline (2234.261 us; speedup 1.0000x reference)
//
#include <hip/hip_runtime.h>
#include <stdint.h>

#define EPS 1e-5f
#define SCALE 0.08838834764831845f  /* 1/sqrt(128) */

typedef __bf16 bf16x8 __attribute__((ext_vector_type(8)));
typedef float f32x4 __attribute__((ext_vector_type(4)));
typedef unsigned short u16;
typedef unsigned int u32;

__device__ __forceinline__ u16 f2bf(float f) {
  union { float f; u32 u; } x; x.f = f;
  u32 r = x.u + 0x7fffu + ((x.u >> 16) & 1u);
  return (u16)(r >> 16);
}
__device__ __forceinline__ float bf2f(u16 u) {
  union { u32 u; float f; } x; x.u = ((u32)u) << 16; return x.f;
}
__device__ __forceinline__ void glds16(const void* g, void* l) {
  __builtin_amdgcn_global_load_lds((__attribute__((address_space(1))) void*)g,
                                   (__attribute__((address_space(3))) void*)l,
                                   16, 0, 0);
}

// ---------------- f32 -> bf16 convert ----------------
__global__ __launch_bounds__(256) void f2b_kernel(const float* __restrict__ in,
                                                  u16* __restrict__ out, int n4) {
  int i = blockIdx.x * 256 + threadIdx.x;
  if (i >= n4) return;
  float4 v = ((const float4*)in)[i];
  ((ushort4*)out)[i] = make_ushort4(f2bf(v.x), f2bf(v.y), f2bf(v.z), f2bf(v.w));
}

// ---------------- main bf16 GEMM: C[m,n] = sum_k A[m,k]*B[n,k] (+bias[n]) ----
// A:[M,K] bf16, B:[N,K] bf16 (weight as given = B^T form), grid (N/128, M/128)
template <int OUT_BF16>
__global__ __launch_bounds__(256)
void gemm_bt(const u16* __restrict__ A, const u16* __restrict__ B,
             const float* __restrict__ bias, float* __restrict__ Cf,
             u16* __restrict__ Cb, int M, int N, int K) {
  __shared__ u16 sA[128 * 32];
  __shared__ u16 sB[128 * 32];
  const int bn0 = blockIdx.x * 128;
  const int bm0 = blockIdx.y * 128;
  const int tid = threadIdx.x;
  const int w = tid >> 6, l = tid & 63;
  const int wr = w >> 1, wc = w & 1;
  const int lr = l & 15, lk = l >> 4;

  f32x4 acc[4][4] = {};

  for (int k0 = 0; k0 < K; k0 += 32) {
#pragma unroll
    for (int i = 0; i < 2; ++i) {
      const int c = (w * 2 + i) * 64 + l;
      const int row = c >> 2, kc = c & 3;
      glds16(A + (size_t)(bm0 + row) * K + k0 + kc * 8, sA + (w * 2 + i) * 512);
      glds16(B + (size_t)(bn0 + row) * K + k0 + kc * 8, sB + (w * 2 + i) * 512);
    }
    __syncthreads();
    bf16x8 af[4], bfr[4];
#pragma unroll
    for (int m = 0; m < 4; ++m)
      af[m] = *(const bf16x8*)(sA + (wr * 64 + m * 16 + lr) * 32 + lk * 8);
#pragma unroll
    for (int n = 0; n < 4; ++n)
      bfr[n] = *(const bf16x8*)(sB + (wc * 64 + n * 16 + lr) * 32 + lk * 8);
#pragma unroll
    for (int m = 0; m < 4; ++m)
#pragma unroll
      for (int n = 0; n < 4; ++n)
        acc[m][n] = __builtin_amdgcn_mfma_f32_16x16x32_bf16(af[m], bfr[n], acc[m][n], 0, 0, 0);
    __syncthreads();
  }

#pragma unroll
  for (int m = 0; m < 4; ++m) {
    const int grow0 = bm0 + wr * 64 + m * 16 + lk * 4;
#pragma unroll
    for (int n = 0; n < 4; ++n) {
      const int gcol = bn0 + wc * 64 + n * 16 + lr;
      const float bv = bias ? bias[gcol] : 0.0f;
#pragma unroll
      for (int i = 0; i < 4; ++i) {
        const float v = acc[m][n][i] + bv;
        const size_t idx = (size_t)(grow0 + i) * N + gcol;
        if (OUT_BF16) Cb[idx] = f2bf(v);
        else Cf[idx] = v;
      }
    }
  }
}

// ---------------- batched score GEMM: S[bh] = q[b]@k[b,h]^T ------------------
// QV: [2048,1024] bf16 (rows b*64+i, cols h*128+d); KB: [32768,1024] bf16
// out: [256, 64, 1024] f32 raw scores. grid (8, 1, 256)
__global__ __launch_bounds__(256)
void score_gemm(const u16* __restrict__ QV, const u16* __restrict__ KB,
                float* __restrict__ out) {
  __shared__ u16 sA[64 * 32];
  __shared__ u16 sB[128 * 32];
  const int bh = blockIdx.z;
  const int b = bh >> 3, h = bh & 7;
  const int bn0 = blockIdx.x * 128;
  const int tid = threadIdx.x;
  const int w = tid >> 6, l = tid & 63;
  const int lr = l & 15, lk = l >> 4;

  const u16* Abase = QV + (size_t)b * 64 * 1024 + h * 128;
  const u16* Bbase = KB + (size_t)b * 1024 * 1024 + (size_t)bn0 * 1024 + h * 128;

  f32x4 acc[4][2] = {};

  for (int k0 = 0; k0 < 128; k0 += 32) {
    {
      const int c = w * 64 + l;
      const int row = c >> 2, kc = c & 3;
      glds16(Abase + (size_t)row * 1024 + k0 + kc * 8, sA + w * 512);
    }
#pragma unroll
    for (int i = 0; i < 2; ++i) {
      const int c = (w * 2 + i) * 64 + l;
      const int row = c >> 2, kc = c & 3;
      glds16(Bbase + (size_t)row * 1024 + k0 + kc * 8, sB + (w * 2 + i) * 512);
    }
    __syncthreads();
    bf16x8 af[4], bfr[2];
#pragma unroll
    for (int m = 0; m < 4; ++m)
      af[m] = *(const bf16x8*)(sA + (m * 16 + lr) * 32 + lk * 8);
#pragma unroll
    for (int n = 0; n < 2; ++n)
      bfr[n] = *(const bf16x8*)(sB + (w * 32 + n * 16 + lr) * 32 + lk * 8);
#pragma unroll
    for (int m = 0; m < 4; ++m)
#pragma unroll
      for (int n = 0; n < 2; ++n)
        acc[m][n] = __builtin_amdgcn_mfma_f32_16x16x32_bf16(af[m], bfr[n], acc[m][n], 0, 0, 0);
    __syncthreads();
  }

  float* C = out + (size_t)bh * 64 * 1024;
#pragma unroll
  for (int m = 0; m < 4; ++m)
#pragma unroll
    for (int n = 0; n < 2; ++n)
#pragma unroll
      for (int i = 0; i < 4; ++i) {
        const int row = m * 16 + lk * 4 + i;
        const int col = bn0 + w * 32 + n * 16 + lr;
        C[(size_t)row * 1024 + col] = acc[m][n][i];
      }
}

// ---------------- vl softmax (in place, with query-mask scale) ---------------
__global__ __launch_bounds__(256)
void vl_softmax(float* __restrict__ S, const float* __restrict__ qmask) {
  __shared__ float red[4];
  const int row = blockIdx.x;          // 16384 = (b*8+h)*64+i
  const int b = row >> 9;
  const int i = row & 63;
  const float scale = qmask[b * 64 + i] * SCALE;
  float* p = S + (size_t)row * 1024;
  const int t = threadIdx.x;
  float4 v = ((const float4*)p)[t];
  v.x *= scale; v.y *= scale; v.z *= scale; v.w *= scale;
  float mx = fmaxf(fmaxf(v.x, v.y), fmaxf(v.z, v.w));
  for (int o = 32; o > 0; o >>= 1) mx = fmaxf(mx, __shfl_xor(mx, o, 64));
  if ((t & 63) == 0) red[t >> 6] = mx;
  __syncthreads();
  mx = fmaxf(fmaxf(red[0], red[1]), fmaxf(red[2], red[3]));
  const float e0 = expf(v.x - mx), e1 = expf(v.y - mx);
  const float e2 = expf(v.z - mx), e3 = expf(v.w - mx);
  float s = e0 + e1 + e2 + e3;
  for (int o = 32; o > 0; o >>= 1) s += __shfl_xor(s, o, 64);
  __syncthreads();
  if ((t & 63) == 0) red[t >> 6] = s;
  __syncthreads();
  s = red[0] + red[1] + red[2] + red[3];
  const float inv = 1.0f / s;
  ((float4*)p)[t] = make_float4(e0 * inv, e1 * inv, e2 * inv, e3 * inv);
}

// ---------------- column stats (BN over all rows) ----------------------------
__global__ __launch_bounds__(256)
void colstats_partial(const float* __restrict__ X, float* __restrict__ ps,
                      float* __restrict__ pq, int rows_per_chunk, int C) {
  const int c = blockIdx.x * 256 + threadIdx.x;
  const int chunk = blockIdx.y;
  const float* p = X + (size_t)chunk * rows_per_chunk * C + c;
  float s = 0.f, q = 0.f;
  for (int r = 0; r < rows_per_chunk; ++r) {
    float v = p[(size_t)r * C];
    s += v; q += v * v;
  }
  ps[chunk * C + c] = s;
  pq[chunk * C + c] = q;
}
__global__ __launch_bounds__(256)
void colstats_final(const float* __restrict__ ps, const float* __restrict__ pq,
                    float2* __restrict__ st, int nchunks, int C, float inv_n) {
  const int c = blockIdx.x * 256 + threadIdx.x;
  float s = 0.f, q = 0.f;
  for (int i = 0; i < nchunks; ++i) { s += ps[i * C + c]; q += pq[i * C + c]; }
  const float m = s * inv_n;
  const float v = q * inv_n - m * m;
  st[c] = make_float2(m, rsqrtf(v + EPS));
}

// ---------------- BN apply ---------------------------------------------------
__global__ __launch_bounds__(256)
void bn_apply_bf16(const float* __restrict__ X, const float2* __restrict__ st,
                   const float* __restrict__ g, const float* __restrict__ be,
                   u16* __restrict__ out) {
  const size_t i = ((size_t)blockIdx.x * 256 + threadIdx.x) * 4;
  const int c = (int)(i & 1023);
  float4 x = *(const float4*)(X + i);
  float xv[4] = {x.x, x.y, x.z, x.w};
  u16 o[4];
#pragma unroll
  for (int j = 0; j < 4; ++j) {
    float2 s = st[c + j];
    o[j] = f2bf((xv[j] - s.x) * s.y * g[c + j] + be[c + j]);
  }
  *(ushort4*)(out + i) = make_ushort4(o[0], o[1], o[2], o[3]);
}
__global__ __launch_bounds__(256)
void bn_apply_f32(const float* __restrict__ X, const float2* __restrict__ st,
                  const float* __restrict__ g, const float* __restrict__ be,
                  float* __restrict__ out) {
  const size_t i = ((size_t)blockIdx.x * 256 + threadIdx.x) * 4;
  const int c = (int)(i & 1023);
  float4 x = *(const float4*)(X + i);
  float xv[4] = {x.x, x.y, x.z, x.w};
  float o[4];
#pragma unroll
  for (int j = 0; j < 4; ++j) {
    float2 s = st[c + j];
    o[j] = (xv[j] - s.x) * s.y * g[c + j] + be[c + j];
  }
  *(float4*)(out + i) = make_float4(o[0], o[1], o[2], o[3]);
}

// ---------------- instance-norm stats over HW per (b,c) ----------------------
__global__ __launch_bounds__(256)
void instats(const float* __restrict__ X, float2* __restrict__ ist) {
  const int c = blockIdx.x * 256 + threadIdx.x;
  const int b = blockIdx.y;
  const float* p = X + (size_t)b * 1048576 + c;
  float s = 0.f, q = 0.f;
  for (int t = 0; t < 1024; ++t) {
    float v = p[(size_t)t * 1024];
    s += v; q += v * v;
  }
  const float m = s * (1.0f / 1024.0f);
  const float var = q * (1.0f / 1024.0f) - m * m;
  ist[b * 1024 + c] = make_float2(m, rsqrtf(var + EPS));
}
__global__ __launch_bounds__(256)
void inorm_apply(const float* __restrict__ X, const float2* __restrict__ ist,
                 u16* __restrict__ out) {
  const size_t i = ((size_t)blockIdx.x * 256 + threadIdx.x) * 4;
  const int b = (int)(i >> 20);
  const int c = (int)(i & 1023);
  float4 x = *(const float4*)(X + i);
  float xv[4] = {x.x, x.y, x.z, x.w};
  u16 o[4];
#pragma unroll
  for (int j = 0; j < 4; ++j) {
    float2 s = ist[b * 1024 + c + j];
    o[j] = f2bf((xv[j] - s.x) * s.y);
  }
  *(ushort4*)(out + i) = make_ushort4(o[0], o[1], o[2], o[3]);
}

// ---------------- small f32 GEMM: out[m,n] = A[m,:]·W[n,:] + bias[n] ---------
// grid (N/256, M); K == 1024
__global__ __launch_bounds__(256)
void small_gemm(const float* __restrict__ A, const float* __restrict__ W,
                const float* __restrict__ bias, float* __restrict__ out,
                int N, int K) {
  __shared__ float sA[1024];
  const int m = blockIdx.y;
  const int n = blockIdx.x * 256 + threadIdx.x;
  for (int i = threadIdx.x; i < K; i += 256) sA[i] = A[(size_t)m * K + i];
  __syncthreads();
  const float4* w4 = (const float4*)(W + (size_t)n * K);
  const float4* a4 = (const float4*)sA;
  float acc = bias ? bias[n] : 0.0f;
  for (int k = 0; k < K / 4; ++k) {
    float4 wv = w4[k], av = a4[k];
    acc += av.x * wv.x + av.y * wv.y + av.z * wv.z + av.w * wv.w;
  }
  out[(size_t)m * N + n] = acc;
}

// ---------------- memory-fuse attention (per batch) --------------------------
__global__ __launch_bounds__(256)
void mem_attn(const float* __restrict__ qmf, const u16* __restrict__ KM,
              const u16* __restrict__ VM, const float* __restrict__ mask,
              float* __restrict__ att_out, float* __restrict__ attv_out) {
  __shared__ float qs[1024];
  __shared__ float sS[512];
  __shared__ float sP[512];
  __shared__ float sM[64];
  const int b = blockIdx.x;
  const int tid = threadIdx.x;
  for (int i = tid; i < 1024; i += 256) qs[i] = qmf[i];
  if (tid < 64) sM[tid] = mask[b * 64 + tid];
  __syncthreads();
  for (int p = tid; p < 512; p += 256) {
    const int h = p >> 6, j = p & 63;
    const u16* kr = KM + (size_t)(b * 64 + j) * 1024 + h * 128;
    float acc = 0.f;
    for (int d = 0; d < 128; ++d) acc += qs[h * 128 + d] * bf2f(kr[d]);
    sS[p] = acc * sM[j] * SCALE;
  }
  __syncthreads();
  if (tid < 8) {
    const int h = tid;
    float mx = -3.4e38f;
    for (int j = 0; j < 64; ++j) mx = fmaxf(mx, sS[h * 64 + j]);
    float sum = 0.f;
    for (int j = 0; j < 64; ++j) {
      float e = expf(sS[h * 64 + j] - mx);
      sP[h * 64 + j] = e; sum += e;
    }
    const float inv = 1.0f / sum;
    for (int j = 0; j < 64; ++j) {
      float pp = sP[h * 64 + j] * inv;
      sP[h * 64 + j] = pp;
      att_out[(size_t)(b * 8 + h) * 64 + j] = pp;
    }
  }
  __syncthreads();
  for (int c = tid; c < 1024; c += 256) {
    const int h = c >> 7;
    float acc = 0.f;
    for (int j = 0; j < 64; ++j)
      acc += sP[h * 64 + j] * sM[j] * bf2f(VM[(size_t)(b * 64 + j) * 1024 + c]);
    attv_out[(size_t)b * 1024 + c] = acc;
  }
}

// ---------------- cur = inorm(concat(neg_tok, mem_out)) ----------------------
__global__ __launch_bounds__(256)
void make_cur(const float* __restrict__ neg, const float* __restrict__ memo,
              float* __restrict__ cur_out, float* __restrict__ curw) {
  const int i = blockIdx.x * 256 + threadIdx.x;   // 32768
  const int b = i >> 10, c = i & 1023;
  const float a = neg[c], x = memo[i];
  const float mean = 0.5f * (a + x);
  const float d = a - mean;
  const float rs = rsqrtf(d * d + EPS);
  const float o0 = d * rs, o1 = -d * rs;
  cur_out[(size_t)(b * 2) * 1024 + c] = o0;
  cur_out[(size_t)(b * 2 + 1) * 1024 + c] = o1;
  curw[(size_t)(b * 2) * 1024 + c] = o0;
  curw[(size_t)(b * 2 + 1) * 1024 + c] = o1;
}

// ---------------- ff attention: 2 keys, wave per row -------------------------
__global__ __launch_bounds__(256)
void ff_attn(const u16* __restrict__ Q, const float* __restrict__ kf,
             const float* __restrict__ vf, float* __restrict__ att_out,
             u16* __restrict__ AV) {
  const int w = threadIdx.x >> 6, l = threadIdx.x & 63;
  const int r = blockIdx.x * 4 + w;
  const int b = r >> 10, t = r & 1023;
  const int h = l >> 3;
  const uint4* qrow = (const uint4*)(Q + (size_t)r * 1024);
  uint4 qa = qrow[2 * l], qb = qrow[2 * l + 1];
  u32 qu[8] = {qa.x, qa.y, qa.z, qa.w, qb.x, qb.y, qb.z, qb.w};
  float qv[16];
#pragma unroll
  for (int i = 0; i < 8; ++i) {
    qv[2 * i] = bf2f((u16)(qu[i] & 0xffffu));
    qv[2 * i + 1] = bf2f((u16)(qu[i] >> 16));
  }
  const float* k0 = kf + (size_t)b * 2048 + l * 16;
  const float* k1 = k0 + 1024;
  float s0 = 0.f, s1 = 0.f;
#pragma unroll
  for (int i = 0; i < 16; ++i) { s0 += qv[i] * k0[i]; s1 += qv[i] * k1[i]; }
#pragma unroll
  for (int o = 1; o < 8; o <<= 1) {
    s0 += __shfl_xor(s0, o, 64);
    s1 += __shfl_xor(s1, o, 64);
  }
  s0 *= SCALE; s1 *= SCALE;
  const float m = fmaxf(s0, s1);
  const float e0 = expf(s0 - m), e1 = expf(s1 - m);
  const float inv = 1.0f / (e0 + e1);
  const float p0 = e0 * inv, p1 = e1 * inv;
  if ((l & 7) == 0) {
    float* o = att_out + ((size_t)(b * 8 + h) * 1024 + t) * 2;
    o[0] = p0; o[1] = p1;
  }
  const float* v0 = vf + (size_t)b * 2048 + l * 16;
  const float* v1 = v0 + 1024;
  u32 packed[8];
#pragma unroll
  for (int i = 0; i < 8; ++i) {
    u16 lo = f2bf(p0 * v0[2 * i] + p1 * v1[2 * i]);
    u16 hi = f2bf(p0 * v0[2 * i + 1] + p1 * v1[2 * i + 1]);
    packed[i] = (u32)lo | ((u32)hi << 16);
  }
  uint4* dst = (uint4*)(AV + (size_t)r * 1024 + l * 16);
  dst[0] = make_uint4(packed[0], packed[1], packed[2], packed[3]);
  dst[1] = make_uint4(packed[4], packed[5], packed[6], packed[7]);
}

// =============================================================================
extern "C" void kernel_launch(void* const* d_in, const int* in_sizes, int n_in,
                              void* d_out, int out_size, void* d_ws, size_t ws_size,
                              hipStream_t stream) {
  (void)in_sizes; (void)n_in; (void)out_size; (void)ws_size;

  const float* src      = (const float*)d_in[0];
  const float* lan      = (const float*)d_in[1];
  /* d_in[2] pos_embed: unused by reference */
  const float* qmask    = (const float*)d_in[3];
  const float* ip_w     = (const float*)d_in[4];
  /* ip_b (d_in[5]) cancels under BN */
  const float* ip_g     = (const float*)d_in[6];
  const float* ip_beta  = (const float*)d_in[7];
  const float* lp_w     = (const float*)d_in[8];
  const float* lp_b     = (const float*)d_in[9];
  const float* mem_tok  = (const float*)d_in[10];
  const float* neg_tok  = (const float*)d_in[11];
  const float* vl_qw    = (const float*)d_in[12];
  const float* vl_qb    = (const float*)d_in[13];
  const float* vl_kw    = (const float*)d_in[14];
  const float* vl_kb    = (const float*)d_in[15];
  /* vl_vw/vl_vb/vl_ow/vl_ob (16..19): dead — vl_out unused downstream */
  const float* mf_qw    = (const float*)d_in[20];
  const float* mf_qb    = (const float*)d_in[21];
  const float* mf_kw    = (const float*)d_in[22];
  const float* mf_kb    = (const float*)d_in[23];
  const float* mf_vw    = (const float*)d_in[24];
  const float* mf_vb    = (const float*)d_in[25];
  const float* mf_ow    = (const float*)d_in[26];
  const float* mf_ob    = (const float*)d_in[27];
  const float* ff_qw    = (const float*)d_in[28];
  const float* ff_qb    = (const float*)d_in[29];
  const float* ff_kw    = (const float*)d_in[30];
  const float* ff_kb    = (const float*)d_in[31];
  const float* ff_vw    = (const float*)d_in[32];
  const float* ff_vb    = (const float*)d_in[33];
  const float* ff_ow    = (const float*)d_in[34];
  const float* ff_ob    = (const float*)d_in[35];
  const float* op_w     = (const float*)d_in[36];
  /* op_b (37) cancels under BN */
  const float* op_g     = (const float*)d_in[38];
  const float* op_beta  = (const float*)d_in[39];

  float* out_final = (float*)d_out;
  float* out_cur   = out_final + 33554432ull;
  float* out_vl    = out_cur + 65536ull;
  float* out_mem   = out_vl + 16777216ull;
  float* out_ff    = out_mem + 16384ull;

  // ---- workspace carve (~378 MB) ----
  char* wp = (char*)d_ws;
  auto take = [&](size_t sz) { char* r = wp; wp += (sz + 255) & ~(size_t)255; return r; };
  float* W0   = (float*)take(134217728);   // [32768,1024] f32: Y1 / ff_out / Z
  u16*   W1   = (u16*)  take(67108864);    // [32768,1024] bf16: src_p, later ff_n
  u16*   W2   = (u16*)  take(67108864);    // [32768,1024] bf16: vl_k, later ff_q
  u16*   SB   = (u16*)  take(67108864);    // [32768,1024] bf16: src, later attv
  u16*   LP   = (u16*)  take(4194304);     // lan_p bf16 [2048,1024]
  u16*   QV   = (u16*)  take(4194304);     // vl q bf16 [2048,1024]
  u16*   KM   = (u16*)  take(4194304);     // mf k bf16 [2048,1024]
  u16*   VM   = (u16*)  take(4194304);     // mf v bf16 [2048,1024]
  u16*   LANB = (u16*)  take(3145728);     // lan bf16 [2048,768]
  u16*   wip  = (u16*)  take(2097152);
  u16*   wlp  = (u16*)  take(1572864);
  u16*   wvq  = (u16*)  take(2097152);
  u16*   wvk  = (u16*)  take(2097152);
  u16*   wmk  = (u16*)  take(2097152);
  u16*   wmv  = (u16*)  take(2097152);
  u16*   wfq  = (u16*)  take(2097152);
  u16*   wfo  = (u16*)  take(2097152);
  u16*   wop  = (u16*)  take(2097152);
  float* qmf   = (float*)take(4096);
  float* attvm = (float*)take(131072);
  float* memo  = (float*)take(131072);
  float* curw  = (float*)take(262144);
  float* kff   = (float*)take(262144);
  float* vff   = (float*)take(262144);
  float* ps    = (float*)take(65536);
  float* pq    = (float*)take(65536);
  float2* st1  = (float2*)take(8192);
  float2* st2  = (float2*)take(8192);
  float2* ist  = (float2*)take(262144);

  const dim3 blk(256);
  auto F2B = [&](const float* in, u16* out, int n) {
    f2b_kernel<<<dim3((n / 4 + 255) / 256), blk, 0, stream>>>(in, out, n / 4);
  };

  // conversions
  F2B(src, SB, 33554432);
  F2B(lan, LANB, 1572864);
  F2B(ip_w, wip, 1048576);
  F2B(lp_w, wlp, 786432);
  F2B(vl_qw, wvq, 1048576);
  F2B(vl_kw, wvk, 1048576);
  F2B(mf_kw, wmk, 1048576);
  F2B(mf_vw, wmv, 1048576);
  F2B(ff_qw, wfq, 1048576);
  F2B(ff_ow, wfo, 1048576);
  F2B(op_w, wop, 1048576);

  // stage 0: input proj + BN -> src_p (bf16 in W1)
  gemm_bt<0><<<dim3(8, 256), blk, 0, stream>>>(SB, wip, nullptr, W0, nullptr, 32768, 1024, 1024);
  colstats_partial<<<dim3(4, 16), blk, 0, stream>>>(W0, ps, pq, 2048, 1024);
  colstats_final<<<dim3(4), blk, 0, stream>>>(ps, pq, st1, 16, 1024, 1.0f / 32768.0f);
  bn_apply_bf16<<<dim3(32768), blk, 0, stream>>>(W0, st1, ip_g, ip_beta, W1);

  // lan proj
  gemm_bt<1><<<dim3(8, 16), blk, 0, stream>>>(LANB, wlp, lp_b, nullptr, LP, 2048, 1024, 768);

  // stage 1 (vl): only vl_att is live downstream
  gemm_bt<1><<<dim3(8, 16), blk, 0, stream>>>(LP, wvq, vl_qb, nullptr, QV, 2048, 1024, 1024);
  gemm_bt<1><<<dim3(8, 256), blk, 0, stream>>>(W1, wvk, vl_kb, nullptr, W2, 32768, 1024, 1024);
  score_gemm<<<dim3(8, 1, 256), blk, 0, stream>>>(QV, W2, out_vl);
  vl_softmax<<<dim3(16384), blk, 0, stream>>>(out_vl, qmask);

  // stage 2 (memory fuse)
  small_gemm<<<dim3(4, 1), blk, 0, stream>>>(mem_tok, mf_qw, mf_qb, qmf, 1024, 1024);
  gemm_bt<1><<<dim3(8, 16), blk, 0, stream>>>(LP, wmk, mf_kb, nullptr, KM, 2048, 1024, 1024);
  gemm_bt<1><<<dim3(8, 16), blk, 0, stream>>>(LP, wmv, mf_vb, nullptr, VM, 2048, 1024, 1024);
  mem_attn<<<dim3(32), blk, 0, stream>>>(qmf, KM, VM, qmask, out_mem, attvm);
  small_gemm<<<dim3(4, 32), blk, 0, stream>>>(attvm, mf_ow, mf_ob, memo, 1024, 1024);
  make_cur<<<dim3(128), blk, 0, stream>>>(neg_tok, memo, out_cur, curw);

  // stage 3 (feature fuse)
  small_gemm<<<dim3(4, 64), blk, 0, stream>>>(curw, ff_kw, ff_kb, kff, 1024, 1024);
  small_gemm<<<dim3(4, 64), blk, 0, stream>>>(curw, ff_vw, ff_vb, vff, 1024, 1024);
  gemm_bt<1><<<dim3(8, 256), blk, 0, stream>>>(W1, wfq, ff_qb, nullptr, W2, 32768, 1024, 1024);
  ff_attn<<<dim3(8192), blk, 0, stream>>>(W2, kff, vff, out_ff, SB);
  gemm_bt<0><<<dim3(8, 256), blk, 0, stream>>>(SB, wfo, ff_ob, W0, nullptr, 32768, 1024, 1024);
  instats<<<dim3(4, 32), blk, 0, stream>>>(W0, ist);
  inorm_apply<<<dim3(32768), blk, 0, stream>>>(W0, ist, W1);
  gemm_bt<0><<<dim3(8, 256), blk, 0, stream>>>(W1, wop, nullptr, W0, nullptr, 32768, 1024, 1024);
  colstats_partial<<<dim3(4, 16), blk, 0, stream>>>(W0, ps, pq, 2048, 1024);
  colstats_final<<<dim3(4), blk, 0, stream>>>(ps, pq, st2, 16, 1024, 1.0f / 32768.0f);
  bn_apply_f32<<<dim3(32768), blk, 0, stream>>>(W0, st2, op_g, op_beta, out_final);
}

// Round 2
// 1278.701 us; speedup vs baseline: 1.7473x; 1.7473x over previous
//
#include <hip/hip_runtime.h>
#include <stdint.h>

#define EPS 1e-5f
#define SCALE 0.08838834764831845f  /* 1/sqrt(128) */

typedef __bf16 bf16x8 __attribute__((ext_vector_type(8)));
typedef float f32x4 __attribute__((ext_vector_type(4)));
typedef unsigned short u16;
typedef unsigned int u32;

__device__ __forceinline__ u16 f2bf(float f) {
  union { float f; u32 u; } x; x.f = f;
  u32 r = x.u + 0x7fffu + ((x.u >> 16) & 1u);
  return (u16)(r >> 16);
}
__device__ __forceinline__ float bf2f(u16 u) {
  union { u32 u; float f; } x; x.u = ((u32)u) << 16; return x.f;
}
__device__ __forceinline__ void glds16(const void* g, void* l) {
  __builtin_amdgcn_global_load_lds((__attribute__((address_space(1))) void*)g,
                                   (__attribute__((address_space(3))) void*)l,
                                   16, 0, 0);
}

// ---------------- f32 -> bf16 convert ----------------
__global__ __launch_bounds__(256) void f2b_kernel(const float* __restrict__ in,
                                                  u16* __restrict__ out, int n4) {
  int i = blockIdx.x * 256 + threadIdx.x;
  if (i >= n4) return;
  float4 v = ((const float4*)in)[i];
  ((ushort4*)out)[i] = make_ushort4(f2bf(v.x), f2bf(v.y), f2bf(v.z), f2bf(v.w));
}

// ---------------- main bf16 GEMM: C[m,n] = sum_k A[m,k]*B[n,k] (+bias[n]) ----
// A:[M,K] bf16, B:[N,K] bf16 (weight as given = B^T form), grid (N/128, M/128)
template <int OUT_BF16>
__global__ __launch_bounds__(256)
void gemm_bt(const u16* __restrict__ A, const u16* __restrict__ B,
             const float* __restrict__ bias, float* __restrict__ Cf,
             u16* __restrict__ Cb, int M, int N, int K) {
  __shared__ u16 sA[128 * 32];
  __shared__ u16 sB[128 * 32];
  const int bn0 = blockIdx.x * 128;
  const int bm0 = blockIdx.y * 128;
  const int tid = threadIdx.x;
  const int w = tid >> 6, l = tid & 63;
  const int wr = w >> 1, wc = w & 1;
  const int lr = l & 15, lk = l >> 4;

  f32x4 acc[4][4] = {};

  for (int k0 = 0; k0 < K; k0 += 32) {
#pragma unroll
    for (int i = 0; i < 2; ++i) {
      const int c = (w * 2 + i) * 64 + l;
      const int row = c >> 2, kc = c & 3;
      glds16(A + (size_t)(bm0 + row) * K + k0 + kc * 8, sA + (w * 2 + i) * 512);
      glds16(B + (size_t)(bn0 + row) * K + k0 + kc * 8, sB + (w * 2 + i) * 512);
    }
    __syncthreads();
    bf16x8 af[4], bfr[4];
#pragma unroll
    for (int m = 0; m < 4; ++m)
      af[m] = *(const bf16x8*)(sA + (wr * 64 + m * 16 + lr) * 32 + lk * 8);
#pragma unroll
    for (int n = 0; n < 4; ++n)
      bfr[n] = *(const bf16x8*)(sB + (wc * 64 + n * 16 + lr) * 32 + lk * 8);
#pragma unroll
    for (int m = 0; m < 4; ++m)
#pragma unroll
      for (int n = 0; n < 4; ++n)
        acc[m][n] = __builtin_amdgcn_mfma_f32_16x16x32_bf16(af[m], bfr[n], acc[m][n], 0, 0, 0);
    __syncthreads();
  }

#pragma unroll
  for (int m = 0; m < 4; ++m) {
    const int grow0 = bm0 + wr * 64 + m * 16 + lk * 4;
#pragma unroll
    for (int n = 0; n < 4; ++n) {
      const int gcol = bn0 + wc * 64 + n * 16 + lr;
      const float bv = bias ? bias[gcol] : 0.0f;
#pragma unroll
      for (int i = 0; i < 4; ++i) {
        const float v = acc[m][n][i] + bv;
        const size_t idx = (size_t)(grow0 + i) * N + gcol;
        if (OUT_BF16) Cb[idx] = f2bf(v);
        else Cf[idx] = v;
      }
    }
  }
}

// ---------------- batched score GEMM: S[bh] = q[b]@k[b,h]^T ------------------
__global__ __launch_bounds__(256)
void score_gemm(const u16* __restrict__ QV, const u16* __restrict__ KB,
                float* __restrict__ out) {
  __shared__ u16 sA[64 * 32];
  __shared__ u16 sB[128 * 32];
  const int bh = blockIdx.z;
  const int b = bh >> 3, h = bh & 7;
  const int bn0 = blockIdx.x * 128;
  const int tid = threadIdx.x;
  const int w = tid >> 6, l = tid & 63;
  const int lr = l & 15, lk = l >> 4;

  const u16* Abase = QV + (size_t)b * 64 * 1024 + h * 128;
  const u16* Bbase = KB + (size_t)b * 1024 * 1024 + (size_t)bn0 * 1024 + h * 128;

  f32x4 acc[4][2] = {};

  for (int k0 = 0; k0 < 128; k0 += 32) {
    {
      const int c = w * 64 + l;
      const int row = c >> 2, kc = c & 3;
      glds16(Abase + (size_t)row * 1024 + k0 + kc * 8, sA + w * 512);
    }
#pragma unroll
    for (int i = 0; i < 2; ++i) {
      const int c = (w * 2 + i) * 64 + l;
      const int row = c >> 2, kc = c & 3;
      glds16(Bbase + (size_t)row * 1024 + k0 + kc * 8, sB + (w * 2 + i) * 512);
    }
    __syncthreads();
    bf16x8 af[4], bfr[2];
#pragma unroll
    for (int m = 0; m < 4; ++m)
      af[m] = *(const bf16x8*)(sA + (m * 16 + lr) * 32 + lk * 8);
#pragma unroll
    for (int n = 0; n < 2; ++n)
      bfr[n] = *(const bf16x8*)(sB + (w * 32 + n * 16 + lr) * 32 + lk * 8);
#pragma unroll
    for (int m = 0; m < 4; ++m)
#pragma unroll
      for (int n = 0; n < 2; ++n)
        acc[m][n] = __builtin_amdgcn_mfma_f32_16x16x32_bf16(af[m], bfr[n], acc[m][n], 0, 0, 0);
    __syncthreads();
  }

  float* C = out + (size_t)bh * 64 * 1024;
#pragma unroll
  for (int m = 0; m < 4; ++m)
#pragma unroll
    for (int n = 0; n < 2; ++n)
#pragma unroll
      for (int i = 0; i < 4; ++i) {
        const int row = m * 16 + lk * 4 + i;
        const int col = bn0 + w * 32 + n * 16 + lr;
        C[(size_t)row * 1024 + col] = acc[m][n][i];
      }
}

// ---------------- vl softmax (in place, with query-mask scale) ---------------
__global__ __launch_bounds__(256)
void vl_softmax(float* __restrict__ S, const float* __restrict__ qmask) {
  __shared__ float red[4];
  const int row = blockIdx.x;          // 16384 = (b*8+h)*64+i
  const int b = row >> 9;
  const int i = row & 63;
  const float scale = qmask[b * 64 + i] * SCALE;
  float* p = S + (size_t)row * 1024;
  const int t = threadIdx.x;
  float4 v = ((const float4*)p)[t];
  v.x *= scale; v.y *= scale; v.z *= scale; v.w *= scale;
  float mx = fmaxf(fmaxf(v.x, v.y), fmaxf(v.z, v.w));
  for (int o = 32; o > 0; o >>= 1) mx = fmaxf(mx, __shfl_xor(mx, o, 64));
  if ((t & 63) == 0) red[t >> 6] = mx;
  __syncthreads();
  mx = fmaxf(fmaxf(red[0], red[1]), fmaxf(red[2], red[3]));
  const float e0 = expf(v.x - mx), e1 = expf(v.y - mx);
  const float e2 = expf(v.z - mx), e3 = expf(v.w - mx);
  float s = e0 + e1 + e2 + e3;
  for (int o = 32; o > 0; o >>= 1) s += __shfl_xor(s, o, 64);
  __syncthreads();
  if ((t & 63) == 0) red[t >> 6] = s;
  __syncthreads();
  s = red[0] + red[1] + red[2] + red[3];
  const float inv = 1.0f / s;
  ((float4*)p)[t] = make_float4(e0 * inv, e1 * inv, e2 * inv, e3 * inv);
}

// ---------------- column stats v2: 256 chunks, float4/lane -------------------
// X:[32768,1024] f32. grid (256): chunk = blockIdx.x owns 128 rows.
// Each thread owns 4 columns. ps/pq: [256][1024] f32.
__global__ __launch_bounds__(256)
void colstats_partial(const float* __restrict__ X, float* __restrict__ ps,
                      float* __restrict__ pq, int rows_per_chunk) {
  const int tid = threadIdx.x;
  const int chunk = blockIdx.x;
  const float* p = X + (size_t)chunk * rows_per_chunk * 1024 + tid * 4;
  float s0 = 0, s1 = 0, s2 = 0, s3 = 0, q0 = 0, q1 = 0, q2 = 0, q3 = 0;
#pragma unroll 4
  for (int r = 0; r < rows_per_chunk; ++r) {
    float4 v = *(const float4*)(p + (size_t)r * 1024);
    s0 += v.x; s1 += v.y; s2 += v.z; s3 += v.w;
    q0 += v.x * v.x; q1 += v.y * v.y; q2 += v.z * v.z; q3 += v.w * v.w;
  }
  ((float4*)(ps + (size_t)chunk * 1024))[tid] = make_float4(s0, s1, s2, s3);
  ((float4*)(pq + (size_t)chunk * 1024))[tid] = make_float4(q0, q1, q2, q3);
}
// reduce 256 chunks -> stats. grid (4), thread owns 1 column.
__global__ __launch_bounds__(256)
void colstats_final(const float* __restrict__ ps, const float* __restrict__ pq,
                    float2* __restrict__ st, int nchunks, float inv_n) {
  const int c = blockIdx.x * 256 + threadIdx.x;
  float s = 0.f, q = 0.f;
#pragma unroll 8
  for (int i = 0; i < nchunks; ++i) {
    s += ps[(size_t)i * 1024 + c];
    q += pq[(size_t)i * 1024 + c];
  }
  const float m = s * inv_n;
  const float v = q * inv_n - m * m;
  st[c] = make_float2(m, rsqrtf(v + EPS));
}

// ---------------- BN apply ---------------------------------------------------
__global__ __launch_bounds__(256)
void bn_apply_bf16(const float* __restrict__ X, const float2* __restrict__ st,
                   const float* __restrict__ g, const float* __restrict__ be,
                   u16* __restrict__ out) {
  const size_t i = ((size_t)blockIdx.x * 256 + threadIdx.x) * 4;
  const int c = (int)(i & 1023);
  float4 x = *(const float4*)(X + i);
  float xv[4] = {x.x, x.y, x.z, x.w};
  u16 o[4];
#pragma unroll
  for (int j = 0; j < 4; ++j) {
    float2 s = st[c + j];
    o[j] = f2bf((xv[j] - s.x) * s.y * g[c + j] + be[c + j]);
  }
  *(ushort4*)(out + i) = make_ushort4(o[0], o[1], o[2], o[3]);
}
__global__ __launch_bounds__(256)
void bn_apply_f32(const float* __restrict__ X, const float2* __restrict__ st,
                  const float* __restrict__ g, const float* __restrict__ be,
                  float* __restrict__ out) {
  const size_t i = ((size_t)blockIdx.x * 256 + threadIdx.x) * 4;
  const int c = (int)(i & 1023);
  float4 x = *(const float4*)(X + i);
  float xv[4] = {x.x, x.y, x.z, x.w};
  float o[4];
#pragma unroll
  for (int j = 0; j < 4; ++j) {
    float2 s = st[c + j];
    o[j] = (xv[j] - s.x) * s.y * g[c + j] + be[c + j];
  }
  *(float4*)(out + i) = make_float4(o[0], o[1], o[2], o[3]);
}

// ---------------- instance-norm stats v2 -------------------------------------
// X:[32][1024][1024]. grid (8 chunks, 32 b); each block: 128 rows of batch b,
// thread owns 4 cols. partials ps/pq[(b*8+chunk)][1024].
__global__ __launch_bounds__(256)
void instats_partial(const float* __restrict__ X, float* __restrict__ ps,
                     float* __restrict__ pq) {
  const int chunk = blockIdx.x, b = blockIdx.y;
  const int tid = threadIdx.x;
  const float* p = X + (size_t)b * 1048576 + (size_t)chunk * 128 * 1024 + tid * 4;
  float s0 = 0, s1 = 0, s2 = 0, s3 = 0, q0 = 0, q1 = 0, q2 = 0, q3 = 0;
#pragma unroll 4
  for (int r = 0; r < 128; ++r) {
    float4 v = *(const float4*)(p + (size_t)r * 1024);
    s0 += v.x; s1 += v.y; s2 += v.z; s3 += v.w;
    q0 += v.x * v.x; q1 += v.y * v.y; q2 += v.z * v.z; q3 += v.w * v.w;
  }
  const size_t o = (size_t)(b * 8 + chunk) * 1024;
  ((float4*)(ps + o))[tid] = make_float4(s0, s1, s2, s3);
  ((float4*)(pq + o))[tid] = make_float4(q0, q1, q2, q3);
}
// grid (32 b); thread owns 4 cols, reduce 8 chunks.
__global__ __launch_bounds__(256)
void instats_final(const float* __restrict__ ps, const float* __restrict__ pq,
                   float2* __restrict__ ist) {
  const int b = blockIdx.x, tid = threadIdx.x;
  float4 s = make_float4(0, 0, 0, 0), q = make_float4(0, 0, 0, 0);
#pragma unroll
  for (int i = 0; i < 8; ++i) {
    const size_t o = (size_t)(b * 8 + i) * 1024;
    float4 vs = ((const float4*)(ps + o))[tid];
    float4 vq = ((const float4*)(pq + o))[tid];
    s.x += vs.x; s.y += vs.y; s.z += vs.z; s.w += vs.w;
    q.x += vq.x; q.y += vq.y; q.z += vq.z; q.w += vq.w;
  }
  const float sv[4] = {s.x, s.y, s.z, s.w};
  const float qv[4] = {q.x, q.y, q.z, q.w};
#pragma unroll
  for (int j = 0; j < 4; ++j) {
    const float m = sv[j] * (1.0f / 1024.0f);
    const float var = qv[j] * (1.0f / 1024.0f) - m * m;
    ist[b * 1024 + tid * 4 + j] = make_float2(m, rsqrtf(var + EPS));
  }
}
__global__ __launch_bounds__(256)
void inorm_apply(const float* __restrict__ X, const float2* __restrict__ ist,
                 u16* __restrict__ out) {
  const size_t i = ((size_t)blockIdx.x * 256 + threadIdx.x) * 4;
  const int b = (int)(i >> 20);
  const int c = (int)(i & 1023);
  float4 x = *(const float4*)(X + i);
  float xv[4] = {x.x, x.y, x.z, x.w};
  u16 o[4];
#pragma unroll
  for (int j = 0; j < 4; ++j) {
    float2 s = ist[b * 1024 + c + j];
    o[j] = f2bf((xv[j] - s.x) * s.y);
  }
  *(ushort4*)(out + i) = make_ushort4(o[0], o[1], o[2], o[3]);
}

// ---------------- small f32 GEMM: out[m,n] = A[m,:]·W[n,:] + bias[n] ---------
__global__ __launch_bounds__(256)
void small_gemm(const float* __restrict__ A, const float* __restrict__ W,
                const float* __restrict__ bias, float* __restrict__ out,
                int N, int K) {
  __shared__ float sA[1024];
  const int m = blockIdx.y;
  const int n = blockIdx.x * 256 + threadIdx.x;
  for (int i = threadIdx.x; i < K; i += 256) sA[i] = A[(size_t)m * K + i];
  __syncthreads();
  const float4* w4 = (const float4*)(W + (size_t)n * K);
  const float4* a4 = (const float4*)sA;
  float acc = bias ? bias[n] : 0.0f;
  for (int k = 0; k < K / 4; ++k) {
    float4 wv = w4[k], av = a4[k];
    acc += av.x * wv.x + av.y * wv.y + av.z * wv.z + av.w * wv.w;
  }
  out[(size_t)m * N + n] = acc;
}

// ---------------- memory-fuse attention (per batch) --------------------------
__global__ __launch_bounds__(256)
void mem_attn(const float* __restrict__ qmf, const u16* __restrict__ KM,
              const u16* __restrict__ VM, const float* __restrict__ mask,
              float* __restrict__ att_out, float* __restrict__ attv_out) {
  __shared__ float qs[1024];
  __shared__ float sS[512];
  __shared__ float sP[512];
  __shared__ float sM[64];
  const int b = blockIdx.x;
  const int tid = threadIdx.x;
  for (int i = tid; i < 1024; i += 256) qs[i] = qmf[i];
  if (tid < 64) sM[tid] = mask[b * 64 + tid];
  __syncthreads();
  for (int p = tid; p < 512; p += 256) {
    const int h = p >> 6, j = p & 63;
    const u16* kr = KM + (size_t)(b * 64 + j) * 1024 + h * 128;
    float acc = 0.f;
    for (int d = 0; d < 128; ++d) acc += qs[h * 128 + d] * bf2f(kr[d]);
    sS[p] = acc * sM[j] * SCALE;
  }
  __syncthreads();
  if (tid < 8) {
    const int h = tid;
    float mx = -3.4e38f;
    for (int j = 0; j < 64; ++j) mx = fmaxf(mx, sS[h * 64 + j]);
    float sum = 0.f;
    for (int j = 0; j < 64; ++j) {
      float e = expf(sS[h * 64 + j] - mx);
      sP[h * 64 + j] = e; sum += e;
    }
    const float inv = 1.0f / sum;
    for (int j = 0; j < 64; ++j) {
      float pp = sP[h * 64 + j] * inv;
      sP[h * 64 + j] = pp;
      att_out[(size_t)(b * 8 + h) * 64 + j] = pp;
    }
  }
  __syncthreads();
  for (int c = tid; c < 1024; c += 256) {
    const int h = c >> 7;
    float acc = 0.f;
    for (int j = 0; j < 64; ++j)
      acc += sP[h * 64 + j] * sM[j] * bf2f(VM[(size_t)(b * 64 + j) * 1024 + c]);
    attv_out[(size_t)b * 1024 + c] = acc;
  }
}

// ---------------- cur = inorm(concat(neg_tok, mem_out)) ----------------------
__global__ __launch_bounds__(256)
void make_cur(const float* __restrict__ neg, const float* __restrict__ memo,
              float* __restrict__ cur_out, float* __restrict__ curw) {
  const int i = blockIdx.x * 256 + threadIdx.x;   // 32768
  const int b = i >> 10, c = i & 1023;
  const float a = neg[c], x = memo[i];
  const float mean = 0.5f * (a + x);
  const float d = a - mean;
  const float rs = rsqrtf(d * d + EPS);
  const float o0 = d * rs, o1 = -d * rs;
  cur_out[(size_t)(b * 2) * 1024 + c] = o0;
  cur_out[(size_t)(b * 2 + 1) * 1024 + c] = o1;
  curw[(size_t)(b * 2) * 1024 + c] = o0;
  curw[(size_t)(b * 2 + 1) * 1024 + c] = o1;
}

// ---------------- ff attention: 2 keys, wave per row -------------------------
__global__ __launch_bounds__(256)
void ff_attn(const u16* __restrict__ Q, const float* __restrict__ kf,
             const float* __restrict__ vf, float* __restrict__ att_out,
             u16* __restrict__ AV) {
  const int w = threadIdx.x >> 6, l = threadIdx.x & 63;
  const int r = blockIdx.x * 4 + w;
  const int b = r >> 10, t = r & 1023;
  const int h = l >> 3;
  const uint4* qrow = (const uint4*)(Q + (size_t)r * 1024);
  uint4 qa = qrow[2 * l], qb = qrow[2 * l + 1];
  u32 qu[8] = {qa.x, qa.y, qa.z, qa.w, qb.x, qb.y, qb.z, qb.w};
  float qv[16];
#pragma unroll
  for (int i = 0; i < 8; ++i) {
    qv[2 * i] = bf2f((u16)(qu[i] & 0xffffu));
    qv[2 * i + 1] = bf2f((u16)(qu[i] >> 16));
  }
  const float* k0 = kf + (size_t)b * 2048 + l * 16;
  const float* k1 = k0 + 1024;
  float s0 = 0.f, s1 = 0.f;
#pragma unroll
  for (int i = 0; i < 16; ++i) { s0 += qv[i] * k0[i]; s1 += qv[i] * k1[i]; }
#pragma unroll
  for (int o = 1; o < 8; o <<= 1) {
    s0 += __shfl_xor(s0, o, 64);
    s1 += __shfl_xor(s1, o, 64);
  }
  s0 *= SCALE; s1 *= SCALE;
  const float m = fmaxf(s0, s1);
  const float e0 = expf(s0 - m), e1 = expf(s1 - m);
  const float inv = 1.0f / (e0 + e1);
  const float p0 = e0 * inv, p1 = e1 * inv;
  if ((l & 7) == 0) {
    float* o = att_out + ((size_t)(b * 8 + h) * 1024 + t) * 2;
    o[0] = p0; o[1] = p1;
  }
  const float* v0 = vf + (size_t)b * 2048 + l * 16;
  const float* v1 = v0 + 1024;
  u32 packed[8];
#pragma unroll
  for (int i = 0; i < 8; ++i) {
    u16 lo = f2bf(p0 * v0[2 * i] + p1 * v1[2 * i]);
    u16 hi = f2bf(p0 * v0[2 * i + 1] + p1 * v1[2 * i + 1]);
    packed[i] = (u32)lo | ((u32)hi << 16);
  }
  uint4* dst = (uint4*)(AV + (size_t)r * 1024 + l * 16);
  dst[0] = make_uint4(packed[0], packed[1], packed[2], packed[3]);
  dst[1] = make_uint4(packed[4], packed[5], packed[6], packed[7]);
}

// =============================================================================
extern "C" void kernel_launch(void* const* d_in, const int* in_sizes, int n_in,
                              void* d_out, int out_size, void* d_ws, size_t ws_size,
                              hipStream_t stream) {
  (void)in_sizes; (void)n_in; (void)out_size; (void)ws_size;

  const float* src      = (const float*)d_in[0];
  const float* lan      = (const float*)d_in[1];
  /* d_in[2] pos_embed: unused by reference */
  const float* qmask    = (const float*)d_in[3];
  const float* ip_w     = (const float*)d_in[4];
  /* ip_b (d_in[5]) cancels under BN */
  const float* ip_g     = (const float*)d_in[6];
  const float* ip_beta  = (const float*)d_in[7];
  const float* lp_w     = (const float*)d_in[8];
  const float* lp_b     = (const float*)d_in[9];
  const float* mem_tok  = (const float*)d_in[10];
  const float* neg_tok  = (const float*)d_in[11];
  const float* vl_qw    = (const float*)d_in[12];
  const float* vl_qb    = (const float*)d_in[13];
  const float* vl_kw    = (const float*)d_in[14];
  const float* vl_kb    = (const float*)d_in[15];
  /* vl_vw/vl_vb/vl_ow/vl_ob (16..19): dead — vl_out unused downstream */
  const float* mf_qw    = (const float*)d_in[20];
  const float* mf_qb    = (const float*)d_in[21];
  const float* mf_kw    = (const float*)d_in[22];
  const float* mf_kb    = (const float*)d_in[23];
  const float* mf_vw    = (const float*)d_in[24];
  const float* mf_vb    = (const float*)d_in[25];
  const float* mf_ow    = (const float*)d_in[26];
  const float* mf_ob    = (const float*)d_in[27];
  const float* ff_qw    = (const float*)d_in[28];
  const float* ff_qb    = (const float*)d_in[29];
  const float* ff_kw    = (const float*)d_in[30];
  const float* ff_kb    = (const float*)d_in[31];
  const float* ff_vw    = (const float*)d_in[32];
  const float* ff_vb    = (const float*)d_in[33];
  const float* ff_ow    = (const float*)d_in[34];
  const float* ff_ob    = (const float*)d_in[35];
  const float* op_w     = (const float*)d_in[36];
  /* op_b (37) cancels under BN */
  const float* op_g     = (const float*)d_in[38];
  const float* op_beta  = (const float*)d_in[39];

  float* out_final = (float*)d_out;
  float* out_cur   = out_final + 33554432ull;
  float* out_vl    = out_cur + 65536ull;
  float* out_mem   = out_vl + 16777216ull;
  float* out_ff    = out_mem + 16384ull;

  // ---- workspace carve ----
  char* wp = (char*)d_ws;
  auto take = [&](size_t sz) { char* r = wp; wp += (sz + 255) & ~(size_t)255; return r; };
  float* W0   = (float*)take(134217728);   // [32768,1024] f32: Y1 / ff_out / Z
  u16*   W1   = (u16*)  take(67108864);    // [32768,1024] bf16: src_p, later ff_n
  u16*   W2   = (u16*)  take(67108864);    // [32768,1024] bf16: vl_k, later ff_q
  u16*   SB   = (u16*)  take(67108864);    // [32768,1024] bf16: src, later attv
  u16*   LP   = (u16*)  take(4194304);     // lan_p bf16 [2048,1024]
  u16*   QV   = (u16*)  take(4194304);     // vl q bf16 [2048,1024]
  u16*   KM   = (u16*)  take(4194304);     // mf k bf16 [2048,1024]
  u16*   VM   = (u16*)  take(4194304);     // mf v bf16 [2048,1024]
  u16*   LANB = (u16*)  take(3145728);     // lan bf16 [2048,768]
  u16*   wip  = (u16*)  take(2097152);
  u16*   wlp  = (u16*)  take(1572864);
  u16*   wvq  = (u16*)  take(2097152);
  u16*   wvk  = (u16*)  take(2097152);
  u16*   wmk  = (u16*)  take(2097152);
  u16*   wmv  = (u16*)  take(2097152);
  u16*   wfq  = (u16*)  take(2097152);
  u16*   wfo  = (u16*)  take(2097152);
  u16*   wop  = (u16*)  take(2097152);
  float* qmf   = (float*)take(4096);
  float* attvm = (float*)take(131072);
  float* memo  = (float*)take(131072);
  float* curw  = (float*)take(262144);
  float* kff   = (float*)take(262144);
  float* vff   = (float*)take(262144);
  float* ps    = (float*)take(1048576);    // [256][1024] partial sums
  float* pq    = (float*)take(1048576);
  float2* st1  = (float2*)take(8192);
  float2* st2  = (float2*)take(8192);
  float2* ist  = (float2*)take(262144);

  const dim3 blk(256);
  auto F2B = [&](const float* in, u16* out, int n) {
    f2b_kernel<<<dim3((n / 4 + 255) / 256), blk, 0, stream>>>(in, out, n / 4);
  };

  // conversions
  F2B(src, SB, 33554432);
  F2B(lan, LANB, 1572864);
  F2B(ip_w, wip, 1048576);
  F2B(lp_w, wlp, 786432);
  F2B(vl_qw, wvq, 1048576);
  F2B(vl_kw, wvk, 1048576);
  F2B(mf_kw, wmk, 1048576);
  F2B(mf_vw, wmv, 1048576);
  F2B(ff_qw, wfq, 1048576);
  F2B(ff_ow, wfo, 1048576);
  F2B(op_w, wop, 1048576);

  // stage 0: input proj + BN -> src_p (bf16 in W1)
  gemm_bt<0><<<dim3(8, 256), blk, 0, stream>>>(SB, wip, nullptr, W0, nullptr, 32768, 1024, 1024);
  colstats_partial<<<dim3(256), blk, 0, stream>>>(W0, ps, pq, 128);
  colstats_final<<<dim3(4), blk, 0, stream>>>(ps, pq, st1, 256, 1.0f / 32768.0f);
  bn_apply_bf16<<<dim3(32768), blk, 0, stream>>>(W0, st1, ip_g, ip_beta, W1);

  // lan proj
  gemm_bt<1><<<dim3(8, 16), blk, 0, stream>>>(LANB, wlp, lp_b, nullptr, LP, 2048, 1024, 768);

  // stage 1 (vl): only vl_att is live downstream
  gemm_bt<1><<<dim3(8, 16), blk, 0, stream>>>(LP, wvq, vl_qb, nullptr, QV, 2048, 1024, 1024);
  gemm_bt<1><<<dim3(8, 256), blk, 0, stream>>>(W1, wvk, vl_kb, nullptr, W2, 32768, 1024, 1024);
  score_gemm<<<dim3(8, 1, 256), blk, 0, stream>>>(QV, W2, out_vl);
  vl_softmax<<<dim3(16384), blk, 0, stream>>>(out_vl, qmask);

  // stage 2 (memory fuse)
  small_gemm<<<dim3(4, 1), blk, 0, stream>>>(mem_tok, mf_qw, mf_qb, qmf, 1024, 1024);
  gemm_bt<1><<<dim3(8, 16), blk, 0, stream>>>(LP, wmk, mf_kb, nullptr, KM, 2048, 1024, 1024);
  gemm_bt<1><<<dim3(8, 16), blk, 0, stream>>>(LP, wmv, mf_vb, nullptr, VM, 2048, 1024, 1024);
  mem_attn<<<dim3(32), blk, 0, stream>>>(qmf, KM, VM, qmask, out_mem, attvm);
  small_gemm<<<dim3(4, 32), blk, 0, stream>>>(attvm, mf_ow, mf_ob, memo, 1024, 1024);
  make_cur<<<dim3(128), blk, 0, stream>>>(neg_tok, memo, out_cur, curw);

  // stage 3 (feature fuse)
  small_gemm<<<dim3(4, 64), blk, 0, stream>>>(curw, ff_kw, ff_kb, kff, 1024, 1024);
  small_gemm<<<dim3(4, 64), blk, 0, stream>>>(curw, ff_vw, ff_vb, vff, 1024, 1024);
  gemm_bt<1><<<dim3(8, 256), blk, 0, stream>>>(W1, wfq, ff_qb, nullptr, W2, 32768, 1024, 1024);
  ff_attn<<<dim3(8192), blk, 0, stream>>>(W2, kff, vff, out_ff, SB);
  gemm_bt<0><<<dim3(8, 256), blk, 0, stream>>>(SB, wfo, ff_ob, W0, nullptr, 32768, 1024, 1024);
  instats_partial<<<dim3(8, 32), blk, 0, stream>>>(W0, ps, pq);
  instats_final<<<dim3(32), blk, 0, stream>>>(ps, pq, ist);
  inorm_apply<<<dim3(32768), blk, 0, stream>>>(W0, ist, W1);
  gemm_bt<0><<<dim3(8, 256), blk, 0, stream>>>(W1, wop, nullptr, W0, nullptr, 32768, 1024, 1024);
  colstats_partial<<<dim3(256), blk, 0, stream>>>(W0, ps, pq, 128);
  colstats_final<<<dim3(4), blk, 0, stream>>>(ps, pq, st2, 256, 1.0f / 32768.0f);
  bn_apply_f32<<<dim3(32768), blk, 0, stream>>>(W0, st2, op_g, op_beta, out_final);
}

// Round 3
// 1105.376 us; speedup vs baseline: 2.0213x; 1.1568x over previous
//
#include <hip/hip_runtime.h>
#include <stdint.h>

#define EPS 1e-5f
#define SCALE 0.08838834764831845f  /* 1/sqrt(128) */

typedef __bf16 bf16x8 __attribute__((ext_vector_type(8)));
typedef float f32x4 __attribute__((ext_vector_type(4)));
typedef unsigned short u16;
typedef unsigned int u32;
typedef u16 u16x8 __attribute__((ext_vector_type(8)));

__device__ __forceinline__ u16 f2bf(float f) {
  union { float f; u32 u; } x; x.f = f;
  u32 r = x.u + 0x7fffu + ((x.u >> 16) & 1u);
  return (u16)(r >> 16);
}
__device__ __forceinline__ float bf2f(u16 u) {
  union { u32 u; float f; } x; x.u = ((u32)u) << 16; return x.f;
}
__device__ __forceinline__ void glds16(const void* g, void* l) {
  __builtin_amdgcn_global_load_lds((__attribute__((address_space(1))) void*)g,
                                   (__attribute__((address_space(3))) void*)l,
                                   16, 0, 0);
}

// ---------------- f32 -> bf16 convert (single big tensor) --------------------
__global__ __launch_bounds__(256) void f2b_kernel(const float* __restrict__ in,
                                                  u16* __restrict__ out, int n4) {
  int i = blockIdx.x * 256 + threadIdx.x;
  if (i >= n4) return;
  float4 v = ((const float4*)in)[i];
  ((ushort4*)out)[i] = make_ushort4(f2bf(v.x), f2bf(v.y), f2bf(v.z), f2bf(v.w));
}

// ---------------- f32 -> bf16 convert, 10 segments in one launch -------------
struct F2B10 {
  const float* in[10];
  u16* out[10];
  int n4[10];
};
__global__ __launch_bounds__(256) void f2b_multi(F2B10 j) {
  const int seg = blockIdx.y;
  const int n4 = j.n4[seg];
  const float* __restrict__ in = j.in[seg];
  u16* __restrict__ out = j.out[seg];
  for (int i = blockIdx.x * 256 + threadIdx.x; i < n4; i += gridDim.x * 256) {
    float4 v = ((const float4*)in)[i];
    ((ushort4*)out)[i] = make_ushort4(f2bf(v.x), f2bf(v.y), f2bf(v.z), f2bf(v.w));
  }
}

// ---------------- main bf16 GEMM: C[m,n] = sum_k A[m,k]*B[n,k] (+bias[n]) ----
// A:[M,K] bf16, B:[N,K] bf16, C bf16. grid (8, M/128). XCD-chunked swizzle.
__global__ __launch_bounds__(256)
void gemm_bt(const u16* __restrict__ A, const u16* __restrict__ B,
             const float* __restrict__ bias, u16* __restrict__ Cb,
             int M, int N, int K) {
  __shared__ u16 sA[128 * 32];
  __shared__ u16 sB[128 * 32];
  // XCD-chunked swizzle (T1): slots s%8==k land on XCD k; give XCD k a
  // contiguous band of tile ids so the 8 N-blocks sharing an A-panel are
  // temporally adjacent on the same L2. Valid: nwg % 8 == 0 for all grids.
  const int nwg = (int)(gridDim.x * gridDim.y);
  const int chunk = nwg >> 3;
  int s = blockIdx.y * gridDim.x + blockIdx.x;
  int t = (s & 7) * chunk + (s >> 3);
  const int bn0 = (t & 7) * 128;
  const int bm0 = (t >> 3) * 128;
  const int tid = threadIdx.x;
  const int w = tid >> 6, l = tid & 63;
  const int wr = w >> 1, wc = w & 1;
  const int lr = l & 15, lk = l >> 4;

  f32x4 acc[4][4] = {};

  for (int k0 = 0; k0 < K; k0 += 32) {
#pragma unroll
    for (int i = 0; i < 2; ++i) {
      const int c = (w * 2 + i) * 64 + l;
      const int row = c >> 2, kc = c & 3;
      glds16(A + (size_t)(bm0 + row) * K + k0 + kc * 8, sA + (w * 2 + i) * 512);
      glds16(B + (size_t)(bn0 + row) * K + k0 + kc * 8, sB + (w * 2 + i) * 512);
    }
    __syncthreads();
    bf16x8 af[4], bfr[4];
#pragma unroll
    for (int m = 0; m < 4; ++m)
      af[m] = *(const bf16x8*)(sA + (wr * 64 + m * 16 + lr) * 32 + lk * 8);
#pragma unroll
    for (int n = 0; n < 4; ++n)
      bfr[n] = *(const bf16x8*)(sB + (wc * 64 + n * 16 + lr) * 32 + lk * 8);
#pragma unroll
    for (int m = 0; m < 4; ++m)
#pragma unroll
      for (int n = 0; n < 4; ++n)
        acc[m][n] = __builtin_amdgcn_mfma_f32_16x16x32_bf16(af[m], bfr[n], acc[m][n], 0, 0, 0);
    __syncthreads();
  }

#pragma unroll
  for (int m = 0; m < 4; ++m) {
    const int grow0 = bm0 + wr * 64 + m * 16 + lk * 4;
#pragma unroll
    for (int n = 0; n < 4; ++n) {
      const int gcol = bn0 + wc * 64 + n * 16 + lr;
      const float bv = bias ? bias[gcol] : 0.0f;
#pragma unroll
      for (int i = 0; i < 4; ++i) {
        const float v = acc[m][n][i] + bv;
        Cb[(size_t)(grow0 + i) * N + gcol] = f2bf(v);
      }
    }
  }
}

// ---------------- batched score GEMM: S[bh] = q[b]@k[b,h]^T ------------------
__global__ __launch_bounds__(256)
void score_gemm(const u16* __restrict__ QV, const u16* __restrict__ KB,
                float* __restrict__ out) {
  __shared__ u16 sA[64 * 32];
  __shared__ u16 sB[128 * 32];
  const int bh = blockIdx.z;
  const int b = bh >> 3, h = bh & 7;
  const int bn0 = blockIdx.x * 128;
  const int tid = threadIdx.x;
  const int w = tid >> 6, l = tid & 63;
  const int lr = l & 15, lk = l >> 4;

  const u16* Abase = QV + (size_t)b * 64 * 1024 + h * 128;
  const u16* Bbase = KB + (size_t)b * 1024 * 1024 + (size_t)bn0 * 1024 + h * 128;

  f32x4 acc[4][2] = {};

  for (int k0 = 0; k0 < 128; k0 += 32) {
    {
      const int c = w * 64 + l;
      const int row = c >> 2, kc = c & 3;
      glds16(Abase + (size_t)row * 1024 + k0 + kc * 8, sA + w * 512);
    }
#pragma unroll
    for (int i = 0; i < 2; ++i) {
      const int c = (w * 2 + i) * 64 + l;
      const int row = c >> 2, kc = c & 3;
      glds16(Bbase + (size_t)row * 1024 + k0 + kc * 8, sB + (w * 2 + i) * 512);
    }
    __syncthreads();
    bf16x8 af[4], bfr[2];
#pragma unroll
    for (int m = 0; m < 4; ++m)
      af[m] = *(const bf16x8*)(sA + (m * 16 + lr) * 32 + lk * 8);
#pragma unroll
    for (int n = 0; n < 2; ++n)
      bfr[n] = *(const bf16x8*)(sB + (w * 32 + n * 16 + lr) * 32 + lk * 8);
#pragma unroll
    for (int m = 0; m < 4; ++m)
#pragma unroll
      for (int n = 0; n < 2; ++n)
        acc[m][n] = __builtin_amdgcn_mfma_f32_16x16x32_bf16(af[m], bfr[n], acc[m][n], 0, 0, 0);
    __syncthreads();
  }

  float* C = out + (size_t)bh * 64 * 1024;
#pragma unroll
  for (int m = 0; m < 4; ++m)
#pragma unroll
    for (int n = 0; n < 2; ++n)
#pragma unroll
      for (int i = 0; i < 4; ++i) {
        const int row = m * 16 + lk * 4 + i;
        const int col = bn0 + w * 32 + n * 16 + lr;
        C[(size_t)row * 1024 + col] = acc[m][n][i];
      }
}

// ---------------- vl softmax (in place, with query-mask scale) ---------------
__global__ __launch_bounds__(256)
void vl_softmax(float* __restrict__ S, const float* __restrict__ qmask) {
  __shared__ float red[4];
  const int row = blockIdx.x;          // 16384 = (b*8+h)*64+i
  const int b = row >> 9;
  const int i = row & 63;
  const float scale = qmask[b * 64 + i] * SCALE;
  float* p = S + (size_t)row * 1024;
  const int t = threadIdx.x;
  float4 v = ((const float4*)p)[t];
  v.x *= scale; v.y *= scale; v.z *= scale; v.w *= scale;
  float mx = fmaxf(fmaxf(v.x, v.y), fmaxf(v.z, v.w));
  for (int o = 32; o > 0; o >>= 1) mx = fmaxf(mx, __shfl_xor(mx, o, 64));
  if ((t & 63) == 0) red[t >> 6] = mx;
  __syncthreads();
  mx = fmaxf(fmaxf(red[0], red[1]), fmaxf(red[2], red[3]));
  const float e0 = expf(v.x - mx), e1 = expf(v.y - mx);
  const float e2 = expf(v.z - mx), e3 = expf(v.w - mx);
  float s = e0 + e1 + e2 + e3;
  for (int o = 32; o > 0; o >>= 1) s += __shfl_xor(s, o, 64);
  __syncthreads();
  if ((t & 63) == 0) red[t >> 6] = s;
  __syncthreads();
  s = red[0] + red[1] + red[2] + red[3];
  const float inv = 1.0f / s;
  ((float4*)p)[t] = make_float4(e0 * inv, e1 * inv, e2 * inv, e3 * inv);
}

// ---------------- column stats over bf16 [32768,1024] ------------------------
// grid (256): chunk owns 128 rows; thread: 8 cols (16B load), half-rows.
// partials ps/pq[(chunk*2+rg)][1024], 512 chunks total.
__global__ __launch_bounds__(256)
void colstats_partial_b(const u16* __restrict__ X, float* __restrict__ ps,
                        float* __restrict__ pq) {
  const int tid = threadIdx.x;
  const int chunk = blockIdx.x;
  const int colb = (tid & 127) * 8;
  const int rg = tid >> 7;
  const u16* p = X + ((size_t)chunk * 128 + rg * 64) * 1024 + colb;
  float s[8] = {}, q[8] = {};
  for (int r = 0; r < 64; ++r) {
    u16x8 v = *(const u16x8*)(p + (size_t)r * 1024);
#pragma unroll
    for (int j = 0; j < 8; ++j) {
      float f = bf2f(v[j]);
      s[j] += f; q[j] += f * f;
    }
  }
  float* dps = ps + (size_t)(chunk * 2 + rg) * 1024 + colb;
  float* dpq = pq + (size_t)(chunk * 2 + rg) * 1024 + colb;
  *(float4*)(dps) = make_float4(s[0], s[1], s[2], s[3]);
  *(float4*)(dps + 4) = make_float4(s[4], s[5], s[6], s[7]);
  *(float4*)(dpq) = make_float4(q[0], q[1], q[2], q[3]);
  *(float4*)(dpq + 4) = make_float4(q[4], q[5], q[6], q[7]);
}
// reduce 512 chunks -> stats. grid (32): block owns 32 cols, 8 chunk-groups.
__global__ __launch_bounds__(256)
void colstats_final(const float* __restrict__ ps, const float* __restrict__ pq,
                    float2* __restrict__ st, float inv_n) {
  __shared__ float rs[8][32], rq[8][32];
  const int cg = threadIdx.x >> 5, cl = threadIdx.x & 31;
  const int col = blockIdx.x * 32 + cl;
  float s = 0.f, q = 0.f;
  for (int i = 0; i < 64; ++i) {
    const size_t idx = (size_t)(cg * 64 + i) * 1024 + col;
    s += ps[idx]; q += pq[idx];
  }
  rs[cg][cl] = s; rq[cg][cl] = q;
  __syncthreads();
  if (cg == 0) {
    for (int i = 1; i < 8; ++i) { s += rs[i][cl]; q += rq[i][cl]; }
    const float m = s * inv_n;
    const float v = q * inv_n - m * m;
    st[col] = make_float2(m, rsqrtf(v + EPS));
  }
}

// ---------------- BN apply (bf16 in) -----------------------------------------
__global__ __launch_bounds__(256)
void bn_apply_bf16(const u16* __restrict__ X, const float2* __restrict__ st,
                   const float* __restrict__ g, const float* __restrict__ be,
                   u16* __restrict__ out) {
  const size_t i = ((size_t)blockIdx.x * 256 + threadIdx.x) * 8;
  const int c = (int)(i & 1023);
  u16x8 x = *(const u16x8*)(X + i);
  u16x8 o;
#pragma unroll
  for (int j = 0; j < 8; ++j) {
    float2 s = st[c + j];
    o[j] = f2bf((bf2f(x[j]) - s.x) * s.y * g[c + j] + be[c + j]);
  }
  *(u16x8*)(out + i) = o;
}
__global__ __launch_bounds__(256)
void bn_apply_f32(const u16* __restrict__ X, const float2* __restrict__ st,
                  const float* __restrict__ g, const float* __restrict__ be,
                  float* __restrict__ out) {
  const size_t i = ((size_t)blockIdx.x * 256 + threadIdx.x) * 8;
  const int c = (int)(i & 1023);
  u16x8 x = *(const u16x8*)(X + i);
  float o[8];
#pragma unroll
  for (int j = 0; j < 8; ++j) {
    float2 s = st[c + j];
    o[j] = (bf2f(x[j]) - s.x) * s.y * g[c + j] + be[c + j];
  }
  *(float4*)(out + i) = make_float4(o[0], o[1], o[2], o[3]);
  *(float4*)(out + i + 4) = make_float4(o[4], o[5], o[6], o[7]);
}

// ---------------- instance-norm stats (bf16 in) ------------------------------
// X:[32][1024][1024] bf16. grid (8, 32): chunk owns 128 rows of batch b;
// thread: 8 cols, half-rows. partials [(b*16 + chunk*2 + rg)][1024].
__global__ __launch_bounds__(256)
void instats_partial_b(const u16* __restrict__ X, float* __restrict__ ps,
                       float* __restrict__ pq) {
  const int chunk = blockIdx.x, b = blockIdx.y;
  const int tid = threadIdx.x;
  const int colb = (tid & 127) * 8;
  const int rg = tid >> 7;
  const u16* p = X + (size_t)b * 1048576 + ((size_t)chunk * 128 + rg * 64) * 1024 + colb;
  float s[8] = {}, q[8] = {};
  for (int r = 0; r < 64; ++r) {
    u16x8 v = *(const u16x8*)(p + (size_t)r * 1024);
#pragma unroll
    for (int j = 0; j < 8; ++j) {
      float f = bf2f(v[j]);
      s[j] += f; q[j] += f * f;
    }
  }
  const size_t o = (size_t)(b * 16 + chunk * 2 + rg) * 1024 + colb;
  *(float4*)(ps + o) = make_float4(s[0], s[1], s[2], s[3]);
  *(float4*)(ps + o + 4) = make_float4(s[4], s[5], s[6], s[7]);
  *(float4*)(pq + o) = make_float4(q[0], q[1], q[2], q[3]);
  *(float4*)(pq + o + 4) = make_float4(q[4], q[5], q[6], q[7]);
}
// grid (32 b); thread owns 4 cols, reduce 16 chunks.
__global__ __launch_bounds__(256)
void instats_final(const float* __restrict__ ps, const float* __restrict__ pq,
                   float2* __restrict__ ist) {
  const int b = blockIdx.x, tid = threadIdx.x;
  float4 s = make_float4(0, 0, 0, 0), q = make_float4(0, 0, 0, 0);
#pragma unroll
  for (int i = 0; i < 16; ++i) {
    const size_t o = (size_t)(b * 16 + i) * 1024;
    float4 vs = ((const float4*)(ps + o))[tid];
    float4 vq = ((const float4*)(pq + o))[tid];
    s.x += vs.x; s.y += vs.y; s.z += vs.z; s.w += vs.w;
    q.x += vq.x; q.y += vq.y; q.z += vq.z; q.w += vq.w;
  }
  const float sv[4] = {s.x, s.y, s.z, s.w};
  const float qv[4] = {q.x, q.y, q.z, q.w};
#pragma unroll
  for (int j = 0; j < 4; ++j) {
    const float m = sv[j] * (1.0f / 1024.0f);
    const float var = qv[j] * (1.0f / 1024.0f) - m * m;
    ist[b * 1024 + tid * 4 + j] = make_float2(m, rsqrtf(var + EPS));
  }
}
__global__ __launch_bounds__(256)
void inorm_apply(const u16* __restrict__ X, const float2* __restrict__ ist,
                 u16* __restrict__ out) {
  const size_t i = ((size_t)blockIdx.x * 256 + threadIdx.x) * 8;
  const int b = (int)(i >> 20);
  const int c = (int)(i & 1023);
  u16x8 x = *(const u16x8*)(X + i);
  u16x8 o;
#pragma unroll
  for (int j = 0; j < 8; ++j) {
    float2 s = ist[b * 1024 + c + j];
    o[j] = f2bf((bf2f(x[j]) - s.x) * s.y);
  }
  *(u16x8*)(out + i) = o;
}

// ---------------- small f32 GEMM: out[m,n] = A[m,:]·W[n,:] + bias[n] ---------
__global__ __launch_bounds__(256)
void small_gemm(const float* __restrict__ A, const float* __restrict__ W,
                const float* __restrict__ bias, float* __restrict__ out,
                int N, int K) {
  __shared__ float sA[1024];
  const int m = blockIdx.y;
  const int n = blockIdx.x * 256 + threadIdx.x;
  for (int i = threadIdx.x; i < K; i += 256) sA[i] = A[(size_t)m * K + i];
  __syncthreads();
  const float4* w4 = (const float4*)(W + (size_t)n * K);
  const float4* a4 = (const float4*)sA;
  float acc = bias ? bias[n] : 0.0f;
  for (int k = 0; k < K / 4; ++k) {
    float4 wv = w4[k], av = a4[k];
    acc += av.x * wv.x + av.y * wv.y + av.z * wv.z + av.w * wv.w;
  }
  out[(size_t)m * N + n] = acc;
}

// ---------------- memory-fuse attention (per batch) --------------------------
__global__ __launch_bounds__(256)
void mem_attn(const float* __restrict__ qmf, const u16* __restrict__ KM,
              const u16* __restrict__ VM, const float* __restrict__ mask,
              float* __restrict__ att_out, float* __restrict__ attv_out) {
  __shared__ float qs[1024];
  __shared__ float sS[512];
  __shared__ float sP[512];
  __shared__ float sM[64];
  const int b = blockIdx.x;
  const int tid = threadIdx.x;
  for (int i = tid; i < 1024; i += 256) qs[i] = qmf[i];
  if (tid < 64) sM[tid] = mask[b * 64 + tid];
  __syncthreads();
  for (int p = tid; p < 512; p += 256) {
    const int h = p >> 6, j = p & 63;
    const u16* kr = KM + (size_t)(b * 64 + j) * 1024 + h * 128;
    float acc = 0.f;
    for (int d = 0; d < 128; ++d) acc += qs[h * 128 + d] * bf2f(kr[d]);
    sS[p] = acc * sM[j] * SCALE;
  }
  __syncthreads();
  if (tid < 8) {
    const int h = tid;
    float mx = -3.4e38f;
    for (int j = 0; j < 64; ++j) mx = fmaxf(mx, sS[h * 64 + j]);
    float sum = 0.f;
    for (int j = 0; j < 64; ++j) {
      float e = expf(sS[h * 64 + j] - mx);
      sP[h * 64 + j] = e; sum += e;
    }
    const float inv = 1.0f / sum;
    for (int j = 0; j < 64; ++j) {
      float pp = sP[h * 64 + j] * inv;
      sP[h * 64 + j] = pp;
      att_out[(size_t)(b * 8 + h) * 64 + j] = pp;
    }
  }
  __syncthreads();
  for (int c = tid; c < 1024; c += 256) {
    const int h = c >> 7;
    float acc = 0.f;
    for (int j = 0; j < 64; ++j)
      acc += sP[h * 64 + j] * sM[j] * bf2f(VM[(size_t)(b * 64 + j) * 1024 + c]);
    attv_out[(size_t)b * 1024 + c] = acc;
  }
}

// ---------------- cur = inorm(concat(neg_tok, mem_out)) ----------------------
__global__ __launch_bounds__(256)
void make_cur(const float* __restrict__ neg, const float* __restrict__ memo,
              float* __restrict__ cur_out, float* __restrict__ curw) {
  const int i = blockIdx.x * 256 + threadIdx.x;   // 32768
  const int b = i >> 10, c = i & 1023;
  const float a = neg[c], x = memo[i];
  const float mean = 0.5f * (a + x);
  const float d = a - mean;
  const float rs = rsqrtf(d * d + EPS);
  const float o0 = d * rs, o1 = -d * rs;
  cur_out[(size_t)(b * 2) * 1024 + c] = o0;
  cur_out[(size_t)(b * 2 + 1) * 1024 + c] = o1;
  curw[(size_t)(b * 2) * 1024 + c] = o0;
  curw[(size_t)(b * 2 + 1) * 1024 + c] = o1;
}

// ---------------- ff attention: 2 keys, wave per row -------------------------
__global__ __launch_bounds__(256)
void ff_attn(const u16* __restrict__ Q, const float* __restrict__ kf,
             const float* __restrict__ vf, float* __restrict__ att_out,
             u16* __restrict__ AV) {
  const int w = threadIdx.x >> 6, l = threadIdx.x & 63;
  const int r = blockIdx.x * 4 + w;
  const int b = r >> 10, t = r & 1023;
  const int h = l >> 3;
  const uint4* qrow = (const uint4*)(Q + (size_t)r * 1024);
  uint4 qa = qrow[2 * l], qb = qrow[2 * l + 1];
  u32 qu[8] = {qa.x, qa.y, qa.z, qa.w, qb.x, qb.y, qb.z, qb.w};
  float qv[16];
#pragma unroll
  for (int i = 0; i < 8; ++i) {
    qv[2 * i] = bf2f((u16)(qu[i] & 0xffffu));
    qv[2 * i + 1] = bf2f((u16)(qu[i] >> 16));
  }
  const float* k0 = kf + (size_t)b * 2048 + l * 16;
  const float* k1 = k0 + 1024;
  float s0 = 0.f, s1 = 0.f;
#pragma unroll
  for (int i = 0; i < 16; ++i) { s0 += qv[i] * k0[i]; s1 += qv[i] * k1[i]; }
#pragma unroll
  for (int o = 1; o < 8; o <<= 1) {
    s0 += __shfl_xor(s0, o, 64);
    s1 += __shfl_xor(s1, o, 64);
  }
  s0 *= SCALE; s1 *= SCALE;
  const float m = fmaxf(s0, s1);
  const float e0 = expf(s0 - m), e1 = expf(s1 - m);
  const float inv = 1.0f / (e0 + e1);
  const float p0 = e0 * inv, p1 = e1 * inv;
  if ((l & 7) == 0) {
    float* o = att_out + ((size_t)(b * 8 + h) * 1024 + t) * 2;
    o[0] = p0; o[1] = p1;
  }
  const float* v0 = vf + (size_t)b * 2048 + l * 16;
  const float* v1 = v0 + 1024;
  u32 packed[8];
#pragma unroll
  for (int i = 0; i < 8; ++i) {
    u16 lo = f2bf(p0 * v0[2 * i] + p1 * v1[2 * i]);
    u16 hi = f2bf(p0 * v0[2 * i + 1] + p1 * v1[2 * i + 1]);
    packed[i] = (u32)lo | ((u32)hi << 16);
  }
  uint4* dst = (uint4*)(AV + (size_t)r * 1024 + l * 16);
  dst[0] = make_uint4(packed[0], packed[1], packed[2], packed[3]);
  dst[1] = make_uint4(packed[4], packed[5], packed[6], packed[7]);
}

// =============================================================================
extern "C" void kernel_launch(void* const* d_in, const int* in_sizes, int n_in,
                              void* d_out, int out_size, void* d_ws, size_t ws_size,
                              hipStream_t stream) {
  (void)in_sizes; (void)n_in; (void)out_size; (void)ws_size;

  const float* src      = (const float*)d_in[0];
  const float* lan      = (const float*)d_in[1];
  /* d_in[2] pos_embed: unused by reference */
  const float* qmask    = (const float*)d_in[3];
  const float* ip_w     = (const float*)d_in[4];
  /* ip_b (d_in[5]) cancels under BN */
  const float* ip_g     = (const float*)d_in[6];
  const float* ip_beta  = (const float*)d_in[7];
  const float* lp_w     = (const float*)d_in[8];
  const float* lp_b     = (const float*)d_in[9];
  const float* mem_tok  = (const float*)d_in[10];
  const float* neg_tok  = (const float*)d_in[11];
  const float* vl_qw    = (const float*)d_in[12];
  const float* vl_qb    = (const float*)d_in[13];
  const float* vl_kw    = (const float*)d_in[14];
  const float* vl_kb    = (const float*)d_in[15];
  /* vl_vw/vl_vb/vl_ow/vl_ob (16..19): dead — vl_out unused downstream */
  const float* mf_qw    = (const float*)d_in[20];
  const float* mf_qb    = (const float*)d_in[21];
  const float* mf_kw    = (const float*)d_in[22];
  const float* mf_kb    = (const float*)d_in[23];
  const float* mf_vw    = (const float*)d_in[24];
  const float* mf_vb    = (const float*)d_in[25];
  const float* mf_ow    = (const float*)d_in[26];
  const float* mf_ob    = (const float*)d_in[27];
  const float* ff_qw    = (const float*)d_in[28];
  const float* ff_qb    = (const float*)d_in[29];
  const float* ff_kw    = (const float*)d_in[30];
  const float* ff_kb    = (const float*)d_in[31];
  const float* ff_vw    = (const float*)d_in[32];
  const float* ff_vb    = (const float*)d_in[33];
  const float* ff_ow    = (const float*)d_in[34];
  const float* ff_ob    = (const float*)d_in[35];
  const float* op_w     = (const float*)d_in[36];
  /* op_b (37) cancels under BN */
  const float* op_g     = (const float*)d_in[38];
  const float* op_beta  = (const float*)d_in[39];

  float* out_final = (float*)d_out;
  float* out_cur   = out_final + 33554432ull;
  float* out_vl    = out_cur + 65536ull;
  float* out_mem   = out_vl + 16777216ull;
  float* out_ff    = out_mem + 16384ull;

  // ---- workspace carve (all-bf16 intermediates; no 128MB f32 buffer) ----
  char* wp = (char*)d_ws;
  auto take = [&](size_t sz) { char* r = wp; wp += (sz + 255) & ~(size_t)255; return r; };
  u16*   W1   = (u16*)  take(67108864);    // src_p -> ff_out -> (dead)
  u16*   W2   = (u16*)  take(67108864);    // Y1 -> vl_k -> ff_q -> ff_n
  u16*   SB   = (u16*)  take(67108864);    // src bf16 -> AV -> Z
  u16*   LP   = (u16*)  take(4194304);     // lan_p bf16 [2048,1024]
  u16*   QV   = (u16*)  take(4194304);     // vl q bf16 [2048,1024]
  u16*   KM   = (u16*)  take(4194304);     // mf k bf16
  u16*   VM   = (u16*)  take(4194304);     // mf v bf16
  u16*   LANB = (u16*)  take(3145728);     // lan bf16 [2048,768]
  u16*   wip  = (u16*)  take(2097152);
  u16*   wlp  = (u16*)  take(1572864);
  u16*   wvq  = (u16*)  take(2097152);
  u16*   wvk  = (u16*)  take(2097152);
  u16*   wmk  = (u16*)  take(2097152);
  u16*   wmv  = (u16*)  take(2097152);
  u16*   wfq  = (u16*)  take(2097152);
  u16*   wfo  = (u16*)  take(2097152);
  u16*   wop  = (u16*)  take(2097152);
  float* qmf   = (float*)take(4096);
  float* attvm = (float*)take(131072);
  float* memo  = (float*)take(131072);
  float* curw  = (float*)take(262144);
  float* kff   = (float*)take(262144);
  float* vff   = (float*)take(262144);
  float* ps    = (float*)take(2097152);    // [512][1024] f32 partials
  float* pq    = (float*)take(2097152);
  float2* st1  = (float2*)take(8192);
  float2* st2  = (float2*)take(8192);
  float2* ist  = (float2*)take(262144);

  const dim3 blk(256);

  // conversions: src (big, own launch) + 10 segments in one launch
  f2b_kernel<<<dim3(32768), blk, 0, stream>>>(src, SB, 8388608);
  {
    F2B10 j;
    const float* ins[10] = {lan, ip_w, lp_w, vl_qw, vl_kw, mf_kw, mf_vw, ff_qw, ff_ow, op_w};
    u16* outs[10] = {LANB, wip, wlp, wvq, wvk, wmk, wmv, wfq, wfo, wop};
    int n4s[10] = {393216, 262144, 196608, 262144, 262144, 262144, 262144, 262144, 262144, 262144};
    for (int i = 0; i < 10; ++i) { j.in[i] = ins[i]; j.out[i] = outs[i]; j.n4[i] = n4s[i]; }
    f2b_multi<<<dim3(1024, 10), blk, 0, stream>>>(j);
  }

  // stage 0: input proj -> Y1 (bf16, W2); BN -> src_p (bf16, W1)
  gemm_bt<<<dim3(8, 256), blk, 0, stream>>>(SB, wip, nullptr, W2, 32768, 1024, 1024);
  colstats_partial_b<<<dim3(256), blk, 0, stream>>>(W2, ps, pq);
  colstats_final<<<dim3(32), blk, 0, stream>>>(ps, pq, st1, 1.0f / 32768.0f);
  bn_apply_bf16<<<dim3(16384), blk, 0, stream>>>(W2, st1, ip_g, ip_beta, W1);

  // lan proj
  gemm_bt<<<dim3(8, 16), blk, 0, stream>>>(LANB, wlp, lp_b, LP, 2048, 1024, 768);

  // stage 1 (vl): only vl_att is live downstream
  gemm_bt<<<dim3(8, 16), blk, 0, stream>>>(LP, wvq, vl_qb, QV, 2048, 1024, 1024);
  gemm_bt<<<dim3(8, 256), blk, 0, stream>>>(W1, wvk, vl_kb, W2, 32768, 1024, 1024);
  score_gemm<<<dim3(8, 1, 256), blk, 0, stream>>>(QV, W2, out_vl);
  vl_softmax<<<dim3(16384), blk, 0, stream>>>(out_vl, qmask);

  // stage 2 (memory fuse)
  small_gemm<<<dim3(4, 1), blk, 0, stream>>>(mem_tok, mf_qw, mf_qb, qmf, 1024, 1024);
  gemm_bt<<<dim3(8, 16), blk, 0, stream>>>(LP, wmk, mf_kb, KM, 2048, 1024, 1024);
  gemm_bt<<<dim3(8, 16), blk, 0, stream>>>(LP, wmv, mf_vb, VM, 2048, 1024, 1024);
  mem_attn<<<dim3(32), blk, 0, stream>>>(qmf, KM, VM, qmask, out_mem, attvm);
  small_gemm<<<dim3(4, 32), blk, 0, stream>>>(attvm, mf_ow, mf_ob, memo, 1024, 1024);
  make_cur<<<dim3(128), blk, 0, stream>>>(neg_tok, memo, out_cur, curw);

  // stage 3 (feature fuse)
  small_gemm<<<dim3(4, 64), blk, 0, stream>>>(curw, ff_kw, ff_kb, kff, 1024, 1024);
  small_gemm<<<dim3(4, 64), blk, 0, stream>>>(curw, ff_vw, ff_vb, vff, 1024, 1024);
  gemm_bt<<<dim3(8, 256), blk, 0, stream>>>(W1, wfq, ff_qb, W2, 32768, 1024, 1024);
  ff_attn<<<dim3(8192), blk, 0, stream>>>(W2, kff, vff, out_ff, SB);
  gemm_bt<<<dim3(8, 256), blk, 0, stream>>>(SB, wfo, ff_ob, W1, 32768, 1024, 1024);
  instats_partial_b<<<dim3(8, 32), blk, 0, stream>>>(W1, ps, pq);
  instats_final<<<dim3(32), blk, 0, stream>>>(ps, pq, ist);
  inorm_apply<<<dim3(16384), blk, 0, stream>>>(W1, ist, W2);
  gemm_bt<<<dim3(8, 256), blk, 0, stream>>>(W2, wop, nullptr, SB, 32768, 1024, 1024);
  colstats_partial_b<<<dim3(256), blk, 0, stream>>>(SB, ps, pq);
  colstats_final<<<dim3(32), blk, 0, stream>>>(ps, pq, st2, 1.0f / 32768.0f);
  bn_apply_f32<<<dim3(16384), blk, 0, stream>>>(SB, st2, op_g, op_beta, out_final);
}

// Round 4
// 1028.582 us; speedup vs baseline: 2.1722x; 1.0747x over previous
//
#include <hip/hip_runtime.h>
#include <stdint.h>

#define EPS 1e-5f
#define SCALE 0.08838834764831845f  /* 1/sqrt(128) */

typedef __bf16 bf16x8 __attribute__((ext_vector_type(8)));
typedef float f32x4 __attribute__((ext_vector_type(4)));
typedef unsigned short u16;
typedef unsigned int u32;
typedef u16 u16x8 __attribute__((ext_vector_type(8)));

__device__ __forceinline__ u16 f2bf(float f) {
  union { float f; u32 u; } x; x.f = f;
  u32 r = x.u + 0x7fffu + ((x.u >> 16) & 1u);
  return (u16)(r >> 16);
}
__device__ __forceinline__ float bf2f(u16 u) {
  union { u32 u; float f; } x; x.u = ((u32)u) << 16; return x.f;
}
__device__ __forceinline__ void glds16(const void* g, void* l) {
  __builtin_amdgcn_global_load_lds((__attribute__((address_space(1))) void*)g,
                                   (__attribute__((address_space(3))) void*)l,
                                   16, 0, 0);
}

// ---------------- f32 -> bf16 convert (single big tensor) --------------------
__global__ __launch_bounds__(256) void f2b_kernel(const float* __restrict__ in,
                                                  u16* __restrict__ out, int n4) {
  int i = blockIdx.x * 256 + threadIdx.x;
  if (i >= n4) return;
  float4 v = ((const float4*)in)[i];
  ((ushort4*)out)[i] = make_ushort4(f2bf(v.x), f2bf(v.y), f2bf(v.z), f2bf(v.w));
}

// ---------------- f32 -> bf16 convert, 10 segments in one launch -------------
struct F2B10 {
  const float* in[10];
  u16* out[10];
  int n4[10];
};
__global__ __launch_bounds__(256) void f2b_multi(F2B10 j) {
  const int seg = blockIdx.y;
  const int n4 = j.n4[seg];
  const float* __restrict__ in = j.in[seg];
  u16* __restrict__ out = j.out[seg];
  for (int i = blockIdx.x * 256 + threadIdx.x; i < n4; i += gridDim.x * 256) {
    float4 v = ((const float4*)in)[i];
    ((ushort4*)out)[i] = make_ushort4(f2bf(v.x), f2bf(v.y), f2bf(v.z), f2bf(v.w));
  }
}

// ---------------- main bf16 GEMM: C[m,n] = sum_k A[m,k]*B[n,k] (+bias[n]) ----
// 128x128 tile, BK=64, 256 threads (2x2 waves), XCD-chunked swizzle (T1),
// T2 LDS XOR-swizzle. Logical byte L of a [128 rows][64 k] bf16 tile (128B
// rows) is stored at physical P = L ^ ((row&7)<<4). global_load_lds writes
// LDS linearly, so the permutation is applied on the GLOBAL source address
// (rule #21); fragment ds_reads XOR with (lr&7) (frag row ≡ lr mod 8).
__global__ __launch_bounds__(256)
void gemm_bt(const u16* __restrict__ A, const u16* __restrict__ B,
             const float* __restrict__ bias, u16* __restrict__ Cb,
             int M, int N, int K) {
  __shared__ u16 sA[128 * 64];
  __shared__ u16 sB[128 * 64];
  const int nwg = (int)(gridDim.x * gridDim.y);
  const int chunk = nwg >> 3;
  int s = blockIdx.y * gridDim.x + blockIdx.x;
  int t = (s & 7) * chunk + (s >> 3);
  const int bn0 = (t & 7) * 128;
  const int bm0 = (t >> 3) * 128;
  const int tid = threadIdx.x;
  const int w = tid >> 6, l = tid & 63;
  const int wr = w >> 1, wc = w & 1;
  const int lr = l & 15, lk = l >> 4;
  const int swz = lr & 7;

  // staging: pass p covers rows p*32 + (tid>>3); element col
  // scol = ((tid&7) ^ ((tid>>3)&7)) * 8  (constant across passes: p*32 ≡ 0 mod 8)
  const int srow = tid >> 3;
  const int scol = ((tid & 7) ^ (srow & 7)) << 3;
  const u16* Ab = A + (size_t)(bm0 + srow) * K + scol;
  const u16* Bb = B + (size_t)(bn0 + srow) * K + scol;
  const size_t rstride32 = (size_t)32 * K;

  f32x4 acc[4][4] = {};

  for (int k0 = 0; k0 < K; k0 += 64) {
#pragma unroll
    for (int p = 0; p < 4; ++p) {
      glds16(Ab + p * rstride32 + k0, sA + p * 2048 + w * 512);
      glds16(Bb + p * rstride32 + k0, sB + p * 2048 + w * 512);
    }
    __syncthreads();
#pragma unroll
    for (int ks = 0; ks < 2; ++ks) {
      const int off = (((ks << 2) + lk) ^ swz) << 3;
      bf16x8 af[4], bfr[4];
#pragma unroll
      for (int m = 0; m < 4; ++m)
        af[m] = *(const bf16x8*)(sA + (wr * 64 + m * 16 + lr) * 64 + off);
#pragma unroll
      for (int n = 0; n < 4; ++n)
        bfr[n] = *(const bf16x8*)(sB + (wc * 64 + n * 16 + lr) * 64 + off);
#pragma unroll
      for (int m = 0; m < 4; ++m)
#pragma unroll
        for (int n = 0; n < 4; ++n)
          acc[m][n] = __builtin_amdgcn_mfma_f32_16x16x32_bf16(af[m], bfr[n], acc[m][n], 0, 0, 0);
    }
    __syncthreads();
  }

#pragma unroll
  for (int m = 0; m < 4; ++m) {
    const int grow0 = bm0 + wr * 64 + m * 16 + lk * 4;
#pragma unroll
    for (int n = 0; n < 4; ++n) {
      const int gcol = bn0 + wc * 64 + n * 16 + lr;
      const float bv = bias ? bias[gcol] : 0.0f;
#pragma unroll
      for (int i = 0; i < 4; ++i) {
        const float v = acc[m][n][i] + bv;
        Cb[(size_t)(grow0 + i) * N + gcol] = f2bf(v);
      }
    }
  }
}

// ---------------- batched score GEMM: S[bh] = q[b]@k[b,h]^T ------------------
__global__ __launch_bounds__(256)
void score_gemm(const u16* __restrict__ QV, const u16* __restrict__ KB,
                float* __restrict__ out) {
  __shared__ u16 sA[64 * 32];
  __shared__ u16 sB[128 * 32];
  const int bh = blockIdx.z;
  const int b = bh >> 3, h = bh & 7;
  const int bn0 = blockIdx.x * 128;
  const int tid = threadIdx.x;
  const int w = tid >> 6, l = tid & 63;
  const int lr = l & 15, lk = l >> 4;

  const u16* Abase = QV + (size_t)b * 64 * 1024 + h * 128;
  const u16* Bbase = KB + (size_t)b * 1024 * 1024 + (size_t)bn0 * 1024 + h * 128;

  f32x4 acc[4][2] = {};

  for (int k0 = 0; k0 < 128; k0 += 32) {
    {
      const int c = w * 64 + l;
      const int row = c >> 2, kc = c & 3;
      glds16(Abase + (size_t)row * 1024 + k0 + kc * 8, sA + w * 512);
    }
#pragma unroll
    for (int i = 0; i < 2; ++i) {
      const int c = (w * 2 + i) * 64 + l;
      const int row = c >> 2, kc = c & 3;
      glds16(Bbase + (size_t)row * 1024 + k0 + kc * 8, sB + (w * 2 + i) * 512);
    }
    __syncthreads();
    bf16x8 af[4], bfr[2];
#pragma unroll
    for (int m = 0; m < 4; ++m)
      af[m] = *(const bf16x8*)(sA + (m * 16 + lr) * 32 + lk * 8);
#pragma unroll
    for (int n = 0; n < 2; ++n)
      bfr[n] = *(const bf16x8*)(sB + (w * 32 + n * 16 + lr) * 32 + lk * 8);
#pragma unroll
    for (int m = 0; m < 4; ++m)
#pragma unroll
      for (int n = 0; n < 2; ++n)
        acc[m][n] = __builtin_amdgcn_mfma_f32_16x16x32_bf16(af[m], bfr[n], acc[m][n], 0, 0, 0);
    __syncthreads();
  }

  float* C = out + (size_t)bh * 64 * 1024;
#pragma unroll
  for (int m = 0; m < 4; ++m)
#pragma unroll
    for (int n = 0; n < 2; ++n)
#pragma unroll
      for (int i = 0; i < 4; ++i) {
        const int row = m * 16 + lk * 4 + i;
        const int col = bn0 + w * 32 + n * 16 + lr;
        C[(size_t)row * 1024 + col] = acc[m][n][i];
      }
}

// ---------------- vl softmax (in place, with query-mask scale) ---------------
__global__ __launch_bounds__(256)
void vl_softmax(float* __restrict__ S, const float* __restrict__ qmask) {
  __shared__ float red[4];
  const int row = blockIdx.x;          // 16384 = (b*8+h)*64+i
  const int b = row >> 9;
  const int i = row & 63;
  const float scale = qmask[b * 64 + i] * SCALE;
  float* p = S + (size_t)row * 1024;
  const int t = threadIdx.x;
  float4 v = ((const float4*)p)[t];
  v.x *= scale; v.y *= scale; v.z *= scale; v.w *= scale;
  float mx = fmaxf(fmaxf(v.x, v.y), fmaxf(v.z, v.w));
  for (int o = 32; o > 0; o >>= 1) mx = fmaxf(mx, __shfl_xor(mx, o, 64));
  if ((t & 63) == 0) red[t >> 6] = mx;
  __syncthreads();
  mx = fmaxf(fmaxf(red[0], red[1]), fmaxf(red[2], red[3]));
  const float e0 = expf(v.x - mx), e1 = expf(v.y - mx);
  const float e2 = expf(v.z - mx), e3 = expf(v.w - mx);
  float s = e0 + e1 + e2 + e3;
  for (int o = 32; o > 0; o >>= 1) s += __shfl_xor(s, o, 64);
  __syncthreads();
  if ((t & 63) == 0) red[t >> 6] = s;
  __syncthreads();
  s = red[0] + red[1] + red[2] + red[3];
  const float inv = 1.0f / s;
  ((float4*)p)[t] = make_float4(e0 * inv, e1 * inv, e2 * inv, e3 * inv);
}

// ---------------- column stats over bf16 [32768,1024] ------------------------
__global__ __launch_bounds__(256)
void colstats_partial_b(const u16* __restrict__ X, float* __restrict__ ps,
                        float* __restrict__ pq) {
  const int tid = threadIdx.x;
  const int chunk = blockIdx.x;
  const int colb = (tid & 127) * 8;
  const int rg = tid >> 7;
  const u16* p = X + ((size_t)chunk * 128 + rg * 64) * 1024 + colb;
  float s[8] = {}, q[8] = {};
  for (int r = 0; r < 64; ++r) {
    u16x8 v = *(const u16x8*)(p + (size_t)r * 1024);
#pragma unroll
    for (int j = 0; j < 8; ++j) {
      float f = bf2f(v[j]);
      s[j] += f; q[j] += f * f;
    }
  }
  float* dps = ps + (size_t)(chunk * 2 + rg) * 1024 + colb;
  float* dpq = pq + (size_t)(chunk * 2 + rg) * 1024 + colb;
  *(float4*)(dps) = make_float4(s[0], s[1], s[2], s[3]);
  *(float4*)(dps + 4) = make_float4(s[4], s[5], s[6], s[7]);
  *(float4*)(dpq) = make_float4(q[0], q[1], q[2], q[3]);
  *(float4*)(dpq + 4) = make_float4(q[4], q[5], q[6], q[7]);
}
// reduce 512 chunks -> stats. grid (32): block owns 32 cols, 8 chunk-groups.
__global__ __launch_bounds__(256)
void colstats_final(const float* __restrict__ ps, const float* __restrict__ pq,
                    float2* __restrict__ st, float inv_n) {
  __shared__ float rs[8][32], rq[8][32];
  const int cg = threadIdx.x >> 5, cl = threadIdx.x & 31;
  const int col = blockIdx.x * 32 + cl;
  float s = 0.f, q = 0.f;
  for (int i = 0; i < 64; ++i) {
    const size_t idx = (size_t)(cg * 64 + i) * 1024 + col;
    s += ps[idx]; q += pq[idx];
  }
  rs[cg][cl] = s; rq[cg][cl] = q;
  __syncthreads();
  if (cg == 0) {
    for (int i = 1; i < 8; ++i) { s += rs[i][cl]; q += rq[i][cl]; }
    const float m = s * inv_n;
    const float v = q * inv_n - m * m;
    st[col] = make_float2(m, rsqrtf(v + EPS));
  }
}

// ---------------- BN apply (bf16 in) -----------------------------------------
__global__ __launch_bounds__(256)
void bn_apply_bf16(const u16* __restrict__ X, const float2* __restrict__ st,
                   const float* __restrict__ g, const float* __restrict__ be,
                   u16* __restrict__ out) {
  const size_t i = ((size_t)blockIdx.x * 256 + threadIdx.x) * 8;
  const int c = (int)(i & 1023);
  u16x8 x = *(const u16x8*)(X + i);
  u16x8 o;
#pragma unroll
  for (int j = 0; j < 8; ++j) {
    float2 s = st[c + j];
    o[j] = f2bf((bf2f(x[j]) - s.x) * s.y * g[c + j] + be[c + j]);
  }
  *(u16x8*)(out + i) = o;
}
__global__ __launch_bounds__(256)
void bn_apply_f32(const u16* __restrict__ X, const float2* __restrict__ st,
                  const float* __restrict__ g, const float* __restrict__ be,
                  float* __restrict__ out) {
  const size_t i = ((size_t)blockIdx.x * 256 + threadIdx.x) * 8;
  const int c = (int)(i & 1023);
  u16x8 x = *(const u16x8*)(X + i);
  float o[8];
#pragma unroll
  for (int j = 0; j < 8; ++j) {
    float2 s = st[c + j];
    o[j] = (bf2f(x[j]) - s.x) * s.y * g[c + j] + be[c + j];
  }
  *(float4*)(out + i) = make_float4(o[0], o[1], o[2], o[3]);
  *(float4*)(out + i + 4) = make_float4(o[4], o[5], o[6], o[7]);
}

// ---------------- instance-norm stats (bf16 in) ------------------------------
__global__ __launch_bounds__(256)
void instats_partial_b(const u16* __restrict__ X, float* __restrict__ ps,
                       float* __restrict__ pq) {
  const int chunk = blockIdx.x, b = blockIdx.y;
  const int tid = threadIdx.x;
  const int colb = (tid & 127) * 8;
  const int rg = tid >> 7;
  const u16* p = X + (size_t)b * 1048576 + ((size_t)chunk * 128 + rg * 64) * 1024 + colb;
  float s[8] = {}, q[8] = {};
  for (int r = 0; r < 64; ++r) {
    u16x8 v = *(const u16x8*)(p + (size_t)r * 1024);
#pragma unroll
    for (int j = 0; j < 8; ++j) {
      float f = bf2f(v[j]);
      s[j] += f; q[j] += f * f;
    }
  }
  const size_t o = (size_t)(b * 16 + chunk * 2 + rg) * 1024 + colb;
  *(float4*)(ps + o) = make_float4(s[0], s[1], s[2], s[3]);
  *(float4*)(ps + o + 4) = make_float4(s[4], s[5], s[6], s[7]);
  *(float4*)(pq + o) = make_float4(q[0], q[1], q[2], q[3]);
  *(float4*)(pq + o + 4) = make_float4(q[4], q[5], q[6], q[7]);
}
// grid (32 b); thread owns 4 cols, reduce 16 chunks.
__global__ __launch_bounds__(256)
void instats_final(const float* __restrict__ ps, const float* __restrict__ pq,
                   float2* __restrict__ ist) {
  const int b = blockIdx.x, tid = threadIdx.x;
  float4 s = make_float4(0, 0, 0, 0), q = make_float4(0, 0, 0, 0);
#pragma unroll
  for (int i = 0; i < 16; ++i) {
    const size_t o = (size_t)(b * 16 + i) * 1024;
    float4 vs = ((const float4*)(ps + o))[tid];
    float4 vq = ((const float4*)(pq + o))[tid];
    s.x += vs.x; s.y += vs.y; s.z += vs.z; s.w += vs.w;
    q.x += vq.x; q.y += vq.y; q.z += vq.z; q.w += vq.w;
  }
  const float sv[4] = {s.x, s.y, s.z, s.w};
  const float qv[4] = {q.x, q.y, q.z, q.w};
#pragma unroll
  for (int j = 0; j < 4; ++j) {
    const float m = sv[j] * (1.0f / 1024.0f);
    const float var = qv[j] * (1.0f / 1024.0f) - m * m;
    ist[b * 1024 + tid * 4 + j] = make_float2(m, rsqrtf(var + EPS));
  }
}
__global__ __launch_bounds__(256)
void inorm_apply(const u16* __restrict__ X, const float2* __restrict__ ist,
                 u16* __restrict__ out) {
  const size_t i = ((size_t)blockIdx.x * 256 + threadIdx.x) * 8;
  const int b = (int)(i >> 20);
  const int c = (int)(i & 1023);
  u16x8 x = *(const u16x8*)(X + i);
  u16x8 o;
#pragma unroll
  for (int j = 0; j < 8; ++j) {
    float2 s = ist[b * 1024 + c + j];
    o[j] = f2bf((bf2f(x[j]) - s.x) * s.y);
  }
  *(u16x8*)(out + i) = o;
}

// ---------------- small f32 GEMM: out[m,n] = A[m,:]·W[n,:] + bias[n] ---------
__global__ __launch_bounds__(256)
void small_gemm(const float* __restrict__ A, const float* __restrict__ W,
                const float* __restrict__ bias, float* __restrict__ out,
                int N, int K) {
  __shared__ float sA[1024];
  const int m = blockIdx.y;
  const int n = blockIdx.x * 256 + threadIdx.x;
  for (int i = threadIdx.x; i < K; i += 256) sA[i] = A[(size_t)m * K + i];
  __syncthreads();
  const float4* w4 = (const float4*)(W + (size_t)n * K);
  const float4* a4 = (const float4*)sA;
  float acc = bias ? bias[n] : 0.0f;
  for (int k = 0; k < K / 4; ++k) {
    float4 wv = w4[k], av = a4[k];
    acc += av.x * wv.x + av.y * wv.y + av.z * wv.z + av.w * wv.w;
  }
  out[(size_t)m * N + n] = acc;
}

// ---------------- memory-fuse attention (per batch) --------------------------
__global__ __launch_bounds__(256)
void mem_attn(const float* __restrict__ qmf, const u16* __restrict__ KM,
              const u16* __restrict__ VM, const float* __restrict__ mask,
              float* __restrict__ att_out, float* __restrict__ attv_out) {
  __shared__ float qs[1024];
  __shared__ float sS[512];
  __shared__ float sP[512];
  __shared__ float sM[64];
  const int b = blockIdx.x;
  const int tid = threadIdx.x;
  for (int i = tid; i < 1024; i += 256) qs[i] = qmf[i];
  if (tid < 64) sM[tid] = mask[b * 64 + tid];
  __syncthreads();
  for (int p = tid; p < 512; p += 256) {
    const int h = p >> 6, j = p & 63;
    const u16* kr = KM + (size_t)(b * 64 + j) * 1024 + h * 128;
    float acc = 0.f;
    for (int d = 0; d < 128; ++d) acc += qs[h * 128 + d] * bf2f(kr[d]);
    sS[p] = acc * sM[j] * SCALE;
  }
  __syncthreads();
  if (tid < 8) {
    const int h = tid;
    float mx = -3.4e38f;
    for (int j = 0; j < 64; ++j) mx = fmaxf(mx, sS[h * 64 + j]);
    float sum = 0.f;
    for (int j = 0; j < 64; ++j) {
      float e = expf(sS[h * 64 + j] - mx);
      sP[h * 64 + j] = e; sum += e;
    }
    const float inv = 1.0f / sum;
    for (int j = 0; j < 64; ++j) {
      float pp = sP[h * 64 + j] * inv;
      sP[h * 64 + j] = pp;
      att_out[(size_t)(b * 8 + h) * 64 + j] = pp;
    }
  }
  __syncthreads();
  for (int c = tid; c < 1024; c += 256) {
    const int h = c >> 7;
    float acc = 0.f;
    for (int j = 0; j < 64; ++j)
      acc += sP[h * 64 + j] * sM[j] * bf2f(VM[(size_t)(b * 64 + j) * 1024 + c]);
    attv_out[(size_t)b * 1024 + c] = acc;
  }
}

// ---------------- cur = inorm(concat(neg_tok, mem_out)) ----------------------
__global__ __launch_bounds__(256)
void make_cur(const float* __restrict__ neg, const float* __restrict__ memo,
              float* __restrict__ cur_out, float* __restrict__ curw) {
  const int i = blockIdx.x * 256 + threadIdx.x;   // 32768
  const int b = i >> 10, c = i & 1023;
  const float a = neg[c], x = memo[i];
  const float mean = 0.5f * (a + x);
  const float d = a - mean;
  const float rs = rsqrtf(d * d + EPS);
  const float o0 = d * rs, o1 = -d * rs;
  cur_out[(size_t)(b * 2) * 1024 + c] = o0;
  cur_out[(size_t)(b * 2 + 1) * 1024 + c] = o1;
  curw[(size_t)(b * 2) * 1024 + c] = o0;
  curw[(size_t)(b * 2 + 1) * 1024 + c] = o1;
}

// ---------------- ff attention: 2 keys, wave per row -------------------------
__global__ __launch_bounds__(256)
void ff_attn(const u16* __restrict__ Q, const float* __restrict__ kf,
             const float* __restrict__ vf, float* __restrict__ att_out,
             u16* __restrict__ AV) {
  const int w = threadIdx.x >> 6, l = threadIdx.x & 63;
  const int r = blockIdx.x * 4 + w;
  const int b = r >> 10, t = r & 1023;
  const int h = l >> 3;
  const uint4* qrow = (const uint4*)(Q + (size_t)r * 1024);
  uint4 qa = qrow[2 * l], qb = qrow[2 * l + 1];
  u32 qu[8] = {qa.x, qa.y, qa.z, qa.w, qb.x, qb.y, qb.z, qb.w};
  float qv[16];
#pragma unroll
  for (int i = 0; i < 8; ++i) {
    qv[2 * i] = bf2f((u16)(qu[i] & 0xffffu));
    qv[2 * i + 1] = bf2f((u16)(qu[i] >> 16));
  }
  const float* k0 = kf + (size_t)b * 2048 + l * 16;
  const float* k1 = k0 + 1024;
  float s0 = 0.f, s1 = 0.f;
#pragma unroll
  for (int i = 0; i < 16; ++i) { s0 += qv[i] * k0[i]; s1 += qv[i] * k1[i]; }
#pragma unroll
  for (int o = 1; o < 8; o <<= 1) {
    s0 += __shfl_xor(s0, o, 64);
    s1 += __shfl_xor(s1, o, 64);
  }
  s0 *= SCALE; s1 *= SCALE;
  const float m = fmaxf(s0, s1);
  const float e0 = expf(s0 - m), e1 = expf(s1 - m);
  const float inv = 1.0f / (e0 + e1);
  const float p0 = e0 * inv, p1 = e1 * inv;
  if ((l & 7) == 0) {
    float* o = att_out + ((size_t)(b * 8 + h) * 1024 + t) * 2;
    o[0] = p0; o[1] = p1;
  }
  const float* v0 = vf + (size_t)b * 2048 + l * 16;
  const float* v1 = v0 + 1024;
  u32 packed[8];
#pragma unroll
  for (int i = 0; i < 8; ++i) {
    u16 lo = f2bf(p0 * v0[2 * i] + p1 * v1[2 * i]);
    u16 hi = f2bf(p0 * v0[2 * i + 1] + p1 * v1[2 * i + 1]);
    packed[i] = (u32)lo | ((u32)hi << 16);
  }
  uint4* dst = (uint4*)(AV + (size_t)r * 1024 + l * 16);
  dst[0] = make_uint4(packed[0], packed[1], packed[2], packed[3]);
  dst[1] = make_uint4(packed[4], packed[5], packed[6], packed[7]);
}

// =============================================================================
extern "C" void kernel_launch(void* const* d_in, const int* in_sizes, int n_in,
                              void* d_out, int out_size, void* d_ws, size_t ws_size,
                              hipStream_t stream) {
  (void)in_sizes; (void)n_in; (void)out_size; (void)ws_size;

  const float* src      = (const float*)d_in[0];
  const float* lan      = (const float*)d_in[1];
  /* d_in[2] pos_embed: unused by reference */
  const float* qmask    = (const float*)d_in[3];
  const float* ip_w     = (const float*)d_in[4];
  /* ip_b (d_in[5]) cancels under BN */
  const float* ip_g     = (const float*)d_in[6];
  const float* ip_beta  = (const float*)d_in[7];
  const float* lp_w     = (const float*)d_in[8];
  const float* lp_b     = (const float*)d_in[9];
  const float* mem_tok  = (const float*)d_in[10];
  const float* neg_tok  = (const float*)d_in[11];
  const float* vl_qw    = (const float*)d_in[12];
  const float* vl_qb    = (const float*)d_in[13];
  const float* vl_kw    = (const float*)d_in[14];
  const float* vl_kb    = (const float*)d_in[15];
  /* vl_vw/vl_vb/vl_ow/vl_ob (16..19): dead — vl_out unused downstream */
  const float* mf_qw    = (const float*)d_in[20];
  const float* mf_qb    = (const float*)d_in[21];
  const float* mf_kw    = (const float*)d_in[22];
  const float* mf_kb    = (const float*)d_in[23];
  const float* mf_vw    = (const float*)d_in[24];
  const float* mf_vb    = (const float*)d_in[25];
  const float* mf_ow    = (const float*)d_in[26];
  const float* mf_ob    = (const float*)d_in[27];
  const float* ff_qw    = (const float*)d_in[28];
  const float* ff_qb    = (const float*)d_in[29];
  const float* ff_kw    = (const float*)d_in[30];
  const float* ff_kb    = (const float*)d_in[31];
  const float* ff_vw    = (const float*)d_in[32];
  const float* ff_vb    = (const float*)d_in[33];
  const float* ff_ow    = (const float*)d_in[34];
  const float* ff_ob    = (const float*)d_in[35];
  const float* op_w     = (const float*)d_in[36];
  /* op_b (37) cancels under BN */
  const float* op_g     = (const float*)d_in[38];
  const float* op_beta  = (const float*)d_in[39];

  float* out_final = (float*)d_out;
  float* out_cur   = out_final + 33554432ull;
  float* out_vl    = out_cur + 65536ull;
  float* out_mem   = out_vl + 16777216ull;
  float* out_ff    = out_mem + 16384ull;

  // ---- workspace carve (all-bf16 intermediates) ----
  char* wp = (char*)d_ws;
  auto take = [&](size_t sz) { char* r = wp; wp += (sz + 255) & ~(size_t)255; return r; };
  u16*   W1   = (u16*)  take(67108864);    // src_p -> ff_out -> (dead)
  u16*   W2   = (u16*)  take(67108864);    // Y1 -> vl_k -> ff_q -> ff_n
  u16*   SB   = (u16*)  take(67108864);    // src bf16 -> AV -> Z
  u16*   LP   = (u16*)  take(4194304);     // lan_p bf16 [2048,1024]
  u16*   QV   = (u16*)  take(4194304);     // vl q bf16 [2048,1024]
  u16*   KM   = (u16*)  take(4194304);     // mf k bf16
  u16*   VM   = (u16*)  take(4194304);     // mf v bf16
  u16*   LANB = (u16*)  take(3145728);     // lan bf16 [2048,768]
  u16*   wip  = (u16*)  take(2097152);
  u16*   wlp  = (u16*)  take(1572864);
  u16*   wvq  = (u16*)  take(2097152);
  u16*   wvk  = (u16*)  take(2097152);
  u16*   wmk  = (u16*)  take(2097152);
  u16*   wmv  = (u16*)  take(2097152);
  u16*   wfq  = (u16*)  take(2097152);
  u16*   wfo  = (u16*)  take(2097152);
  u16*   wop  = (u16*)  take(2097152);
  float* qmf   = (float*)take(4096);
  float* attvm = (float*)take(131072);
  float* memo  = (float*)take(131072);
  float* curw  = (float*)take(262144);
  float* kff   = (float*)take(262144);
  float* vff   = (float*)take(262144);
  float* ps    = (float*)take(2097152);    // [512][1024] f32 partials
  float* pq    = (float*)take(2097152);
  float2* st1  = (float2*)take(8192);
  float2* st2  = (float2*)take(8192);
  float2* ist  = (float2*)take(262144);

  const dim3 blk(256);

  // conversions: src (big, own launch) + 10 segments in one launch
  f2b_kernel<<<dim3(32768), blk, 0, stream>>>(src, SB, 8388608);
  {
    F2B10 j;
    const float* ins[10] = {lan, ip_w, lp_w, vl_qw, vl_kw, mf_kw, mf_vw, ff_qw, ff_ow, op_w};
    u16* outs[10] = {LANB, wip, wlp, wvq, wvk, wmk, wmv, wfq, wfo, wop};
    int n4s[10] = {393216, 262144, 196608, 262144, 262144, 262144, 262144, 262144, 262144, 262144};
    for (int i = 0; i < 10; ++i) { j.in[i] = ins[i]; j.out[i] = outs[i]; j.n4[i] = n4s[i]; }
    f2b_multi<<<dim3(1024, 10), blk, 0, stream>>>(j);
  }

  // stage 0: input proj -> Y1 (bf16, W2); BN -> src_p (bf16, W1)
  gemm_bt<<<dim3(8, 256), blk, 0, stream>>>(SB, wip, nullptr, W2, 32768, 1024, 1024);
  colstats_partial_b<<<dim3(256), blk, 0, stream>>>(W2, ps, pq);
  colstats_final<<<dim3(32), blk, 0, stream>>>(ps, pq, st1, 1.0f / 32768.0f);
  bn_apply_bf16<<<dim3(16384), blk, 0, stream>>>(W2, st1, ip_g, ip_beta, W1);

  // lan proj
  gemm_bt<<<dim3(8, 16), blk, 0, stream>>>(LANB, wlp, lp_b, LP, 2048, 1024, 768);

  // stage 1 (vl): only vl_att is live downstream
  gemm_bt<<<dim3(8, 16), blk, 0, stream>>>(LP, wvq, vl_qb, QV, 2048, 1024, 1024);
  gemm_bt<<<dim3(8, 256), blk, 0, stream>>>(W1, wvk, vl_kb, W2, 32768, 1024, 1024);
  score_gemm<<<dim3(8, 1, 256), blk, 0, stream>>>(QV, W2, out_vl);
  vl_softmax<<<dim3(16384), blk, 0, stream>>>(out_vl, qmask);

  // stage 2 (memory fuse)
  small_gemm<<<dim3(4, 1), blk, 0, stream>>>(mem_tok, mf_qw, mf_qb, qmf, 1024, 1024);
  gemm_bt<<<dim3(8, 16), blk, 0, stream>>>(LP, wmk, mf_kb, KM, 2048, 1024, 1024);
  gemm_bt<<<dim3(8, 16), blk, 0, stream>>>(LP, wmv, mf_vb, VM, 2048, 1024, 1024);
  mem_attn<<<dim3(32), blk, 0, stream>>>(qmf, KM, VM, qmask, out_mem, attvm);
  small_gemm<<<dim3(4, 32), blk, 0, stream>>>(attvm, mf_ow, mf_ob, memo, 1024, 1024);
  make_cur<<<dim3(128), blk, 0, stream>>>(neg_tok, memo, out_cur, curw);

  // stage 3 (feature fuse)
  small_gemm<<<dim3(4, 64), blk, 0, stream>>>(curw, ff_kw, ff_kb, kff, 1024, 1024);
  small_gemm<<<dim3(4, 64), blk, 0, stream>>>(curw, ff_vw, ff_vb, vff, 1024, 1024);
  gemm_bt<<<dim3(8, 256), blk, 0, stream>>>(W1, wfq, ff_qb, W2, 32768, 1024, 1024);
  ff_attn<<<dim3(8192), blk, 0, stream>>>(W2, kff, vff, out_ff, SB);
  gemm_bt<<<dim3(8, 256), blk, 0, stream>>>(SB, wfo, ff_ob, W1, 32768, 1024, 1024);
  instats_partial_b<<<dim3(8, 32), blk, 0, stream>>>(W1, ps, pq);
  instats_final<<<dim3(32), blk, 0, stream>>>(ps, pq, ist);
  inorm_apply<<<dim3(16384), blk, 0, stream>>>(W1, ist, W2);
  gemm_bt<<<dim3(8, 256), blk, 0, stream>>>(W2, wop, nullptr, SB, 32768, 1024, 1024);
  colstats_partial_b<<<dim3(256), blk, 0, stream>>>(SB, ps, pq);
  colstats_final<<<dim3(32), blk, 0, stream>>>(ps, pq, st2, 1.0f / 32768.0f);
  bn_apply_f32<<<dim3(16384), blk, 0, stream>>>(SB, st2, op_g, op_beta, out_final);
}